// Round 8
// baseline (270.317 us; speedup 1.0000x reference)
//
#include <hip/hip_runtime.h>
#include <hip/hip_bf16.h>
#include <cstdint>

typedef unsigned short ushortT;
typedef __attribute__((ext_vector_type(8))) short short8;
typedef __attribute__((ext_vector_type(4))) float f32x4;

// ---------------- problem constants ----------------
static constexpr int Bn = 4, Cc = 48, Hh = 64, Wd = 64, HW = 4096;
static constexpr int HID = 96, NSET = 32, INTERC = 24, HEADS = 8, CPH = 6;

// ---------------- ws layout (float offsets) ----------------
static constexpr int FXN   = 0;         // 786432  xn fp32 planar (c2a halo use)
static constexpr int FA    = 786432;    // 1572864 t1 ; later Sp
static constexpr int FB    = 2359296;   // 1572864 t2
static constexpr int FC    = 3932160;   // 1572864 x1g -> qkv (spans C+D)
static constexpr int FD    = 5505024;   // 1572864 uf
static constexpr int FARAW = 7077888;   // 393216
static constexpr int FATT  = 7471104;   // 524288  attn_t fp32 [p][32]
static constexpr int FGAP  = 8781824;   // 192
static constexpr int FCA1  = 8782016;   // 192
static constexpr int FCA2  = 8782208;   // 192
static constexpr int FS    = 8782400;   // 1152 Smat
static constexpr int FW    = 8783552;   // 147200 fp32 weights
static constexpr int FATTB = 8930752;   // 262144 fl: att_bf [p][32] bf16
static constexpr int FWT   = 9192896;   // 61440 fl: Wt bf16 (KBA)
static constexpr int FXNB  = 9254336;   // 524288 fl: xnb [p][64] bf16
static constexpr int FXMB  = 9778624;   // 524288 fl: xmb [p][64] bf16
static constexpr int FHBF  = 10302912;  // 786432 fl: h_bf [p][96] bf16
static constexpr int FWPW  = 11089344;  // 7168 fl: Wpw [224][64] bf16
static constexpr int FWQK  = 11096512;  // 4608 fl: Wqk [144][64] bf16
static constexpr int FWKP  = 11101120;  // 2304 fl: Wkp [48][96] bf16
static constexpr int FWMP  = 11103424;  // 1536 fl: Wmp [48][64] bf16
static constexpr int FCNT  = 11104960;  // 64 fl: atomic counter
static constexpr int FQKVR = 11105024;  // 2359296 fl: qkvr planar
// total = 13464320 floats = 53.9 MB

// ---- weight offsets inside FW ----
static constexpr int W_N1W=0, W_N1B=48, W_N2W=96, W_N2B=144;
static constexpr int W_KDW1=192, W_KDW2=4800, W_KC1A=5664, W_KC1B=10272;
static constexpr int W_KPROJ=11136, W_C2AW=15744, W_C2AB=16176;
static constexpr int W_C2BW=16200, W_C2BB=16584, W_C211W=16616, W_C211B=18152;
static constexpr int W_KW=18184, W_KB=128776, W_ATTG=131848, W_GA1=131880;
static constexpr int W_TEMP=131976, W_QKVW=131984, W_QKVDW=138896, W_MPROJ=140192;
static constexpr int W_CA1W=142496, W_CA1B=144800, W_CA2W=144848, W_CA2B=147152;

__device__ __forceinline__ float b2f(ushortT u) {
    union { uint32_t i; float f; } v; v.i = ((uint32_t)u) << 16; return v.f;
}
__device__ __forceinline__ ushortT f2b(float f) {
    union { float f; uint32_t i; } v; v.f = f;
    uint32_t i = v.i;
    uint32_t lsb = (i >> 16) & 1u;
    i += 0x7fffu + lsb;
    return (ushortT)(i >> 16);
}
__device__ __forceinline__ int dtype_bf16(const uint32_t* n1w_raw) {
    return n1w_raw[0] == 0x3F803F80u;
}
__device__ __forceinline__ ushortT raw_bf(const void* p, int idx, int fl) {
    return fl ? ((const ushortT*)p)[idx] : f2b(((const float*)p)[idx]);
}
__device__ __forceinline__ float raw_f(const void* p, int idx, int fl) {
    return fl ? b2f(((const ushortT*)p)[idx]) : ((const float*)p)[idx];
}

// ---------------- prep: convert + all bf16 weight matrices + gap + LN + counter zero ----------------
struct ConvPack {
    const void* src[27];
    int dstoff[27];
    int n[27];
};
struct RawW {
    const void* kdw1; const void* kc1a; const void* c211w; const void* qkvw;
    const void* kproj; const void* mproj; const void* kw; const void* kb;
    const void* n1w; const void* n1b; const void* n2w; const void* n2b;
};

__global__ void k_prep(ConvPack p, RawW rw, float* __restrict__ dst,
                       ushortT* __restrict__ Wt, ushortT* __restrict__ Wpw,
                       ushortT* __restrict__ Wqk, ushortT* __restrict__ Wkp,
                       ushortT* __restrict__ Wmp,
                       const void* __restrict__ x, float* __restrict__ gap,
                       float* __restrict__ xn, ushortT* __restrict__ xnb,
                       ushortT* __restrict__ xmb, unsigned* __restrict__ cnt,
                       const uint32_t* __restrict__ n1w_raw) {
    int fl = dtype_bf16(n1w_raw);
    int y = blockIdx.y;
    if (y < 27) {
        int n = p.n[y];
        for (int i = blockIdx.x * 256 + threadIdx.x; i < n; i += 64 * 256) {
            dst[p.dstoff[y] + i] = raw_f(p.src[y], i, fl);
        }
    } else if (y == 27) {
        for (int u = blockIdx.x * 256 + threadIdx.x; u < 24 * 160 * 32; u += 64 * 256) {
            int n = u & 31;
            int rest = u >> 5;
            int r = rest % 160;
            int gr = rest / 160;
            ushortT out;
            if (r < 144) {
                int j = r >> 2, i = r & 3;
                out = raw_bf(rw.kw, n * 3456 + gr * 144 + i * 36 + j, fl);
            } else if (r < 148) {
                out = raw_bf(rw.kb, n * HID + gr * 4 + (r - 144), fl);
            } else out = 0;
            Wt[u] = out;
        }
    } else if (y == 28) {
        for (int u = blockIdx.x * 256 + threadIdx.x; u < 224 * 64; u += 64 * 256) {
            int co = u >> 6, c = u & 63;
            ushortT v = 0;
            if (c < 48) {
                if (co < 96)       v = raw_bf(rw.kdw1,  co * 48 + c, fl);
                else if (co < 192) v = raw_bf(rw.kc1a,  (co - 96) * 48 + c, fl);
                else               v = raw_bf(rw.c211w, (co - 192) * 48 + c, fl);
            }
            Wpw[u] = v;
        }
    } else if (y == 29) {
        for (int u = blockIdx.x * 256 + threadIdx.x; u < 144 * 64; u += 64 * 256) {
            int co = u >> 6, c = u & 63;
            Wqk[u] = (c < 48) ? raw_bf(rw.qkvw, co * 48 + c, fl) : (ushortT)0;
        }
    } else if (y == 30) {
        for (int u = blockIdx.x * 256 + threadIdx.x; u < 48 * 96; u += 64 * 256) {
            int co = u / 96, c = u % 96;
            Wkp[u] = raw_bf(rw.kproj, co * 96 + c, fl);
        }
    } else if (y == 31) {
        for (int u = blockIdx.x * 256 + threadIdx.x; u < 48 * 64; u += 64 * 256) {
            int co = u >> 6, c = u & 63;
            Wmp[u] = (c < 48) ? raw_bf(rw.mproj, co * 48 + c, fl) : (ushortT)0;
        }
    } else if (y == 32) {
        if (blockIdx.x == 0 && threadIdx.x == 0) cnt[0] = 0u;
        __shared__ float red[4];
        for (int bc = blockIdx.x; bc < Bn * Cc; bc += 64) {
            float s = 0.f;
            if (fl) {
                const ushortT* xb = (const ushortT*)x + bc * HW;
                for (int i = threadIdx.x; i < HW; i += 256) s += b2f(xb[i]);
            } else {
                const float* xb = (const float*)x + bc * HW;
                for (int i = threadIdx.x; i < HW; i += 256) s += xb[i];
            }
            #pragma unroll
            for (int o = 32; o > 0; o >>= 1) s += __shfl_down(s, o);
            int lane = threadIdx.x & 63, wv = threadIdx.x >> 6;
            if (lane == 0) red[wv] = s;
            __syncthreads();
            if (threadIdx.x == 0)
                gap[bc] = (red[0] + red[1] + red[2] + red[3]) * (1.f / HW);
            __syncthreads();
        }
    } else {
        // LN1 + LN2 from raw weights
        int pp = blockIdx.x * 256 + threadIdx.x;
        int b = pp >> 12, hw = pp & 4095;
        float xr[Cc];
        if (fl) {
            const ushortT* xb = (const ushortT*)x + b * Cc * HW + hw;
            #pragma unroll
            for (int c = 0; c < Cc; c++) xr[c] = b2f(xb[c * HW]);
        } else {
            const float* xb = (const float*)x + b * Cc * HW + hw;
            #pragma unroll
            for (int c = 0; c < Cc; c++) xr[c] = xb[c * HW];
        }
        float s = 0.f, ss = 0.f;
        #pragma unroll
        for (int c = 0; c < Cc; c++) { s += xr[c]; ss += xr[c] * xr[c]; }
        float mu = s * (1.f / Cc);
        float var = ss * (1.f / Cc) - mu * mu;
        float r = rsqrtf(var + 1e-6f);
        uint32_t pn[32], pm[32];
        #pragma unroll
        for (int i = 0; i < 24; i++) {
            float y0 = (xr[2 * i] - mu) * r, y1 = (xr[2 * i + 1] - mu) * r;
            float n0 = raw_f(rw.n1w, 2 * i, fl) * y0 + raw_f(rw.n1b, 2 * i, fl);
            float n1 = raw_f(rw.n1w, 2 * i + 1, fl) * y1 + raw_f(rw.n1b, 2 * i + 1, fl);
            float m0 = raw_f(rw.n2w, 2 * i, fl) * y0 + raw_f(rw.n2b, 2 * i, fl);
            float m1 = raw_f(rw.n2w, 2 * i + 1, fl) * y1 + raw_f(rw.n2b, 2 * i + 1, fl);
            xn[(b * Cc + 2 * i) * HW + hw] = n0;
            xn[(b * Cc + 2 * i + 1) * HW + hw] = n1;
            pn[i] = (uint32_t)f2b(n0) | ((uint32_t)f2b(n1) << 16);
            pm[i] = (uint32_t)f2b(m0) | ((uint32_t)f2b(m1) << 16);
        }
        #pragma unroll
        for (int i = 24; i < 32; i++) { pn[i] = 0; pm[i] = 0; }
        uint4* dn = (uint4*)(xnb + (size_t)pp * 64);
        uint4* dm = (uint4*)(xmb + (size_t)pp * 64);
        #pragma unroll
        for (int qd = 0; qd < 8; qd++) {
            uint4 v; v.x = pn[qd*4]; v.y = pn[qd*4+1]; v.z = pn[qd*4+2]; v.w = pn[qd*4+3];
            dn[qd] = v;
            uint4 u; u.x = pm[qd*4]; u.y = pm[qd*4+1]; u.z = pm[qd*4+2]; u.w = pm[qd*4+3];
            dm[qd] = u;
        }
    }
}

// ---------------- pw1m: [224x48]@xnb -> t1,t2,attn_t  AND  [144x48]@xmb -> qkvr. grid 256 x 256 ----------------
__global__ void __launch_bounds__(256) k_pw1m(const ushortT* __restrict__ xnb, const ushortT* __restrict__ xmb,
                       const ushortT* __restrict__ Wpw, const ushortT* __restrict__ Wqk,
                       const float* __restrict__ wts, float* __restrict__ t1,
                       float* __restrict__ t2, float* __restrict__ attn_t,
                       float* __restrict__ qkvr) {
    int wave = threadIdx.x >> 6, lane = threadIdx.x & 63;
    int m = lane & 15, q = lane >> 4;
    int p = blockIdx.x * 64 + wave * 16 + m;
    int b = p >> 12, hw = p & 4095;
    short8 B0 = *(const short8*)(xnb + (size_t)p * 64 + q * 8);
    short8 B1 = *(const short8*)(xnb + (size_t)p * 64 + 32 + q * 8);
    #pragma unroll
    for (int t = 0; t < 14; t++) {
        short8 A0 = *(const short8*)(Wpw + (16 * t + m) * 64 + q * 8);
        short8 A1 = *(const short8*)(Wpw + (16 * t + m) * 64 + 32 + q * 8);
        f32x4 z = {0.f, 0.f, 0.f, 0.f};
        f32x4 D = __builtin_amdgcn_mfma_f32_16x16x32_bf16(A0, B0, z, 0, 0, 0);
        D = __builtin_amdgcn_mfma_f32_16x16x32_bf16(A1, B1, D, 0, 0, 0);
        #pragma unroll
        for (int g = 0; g < 4; g++) {
            int co = 16 * t + 4 * q + g;
            if (t < 6) t1[(b * HID + co) * HW + hw] = D[g];
            else if (t < 12) t2[(b * HID + (co - 96)) * HW + hw] = D[g];
            else {
                int n = co - 192;
                attn_t[(size_t)p * 32 + n] = D[g] + wts[W_C211B + n];
            }
        }
    }
    short8 C0 = *(const short8*)(xmb + (size_t)p * 64 + q * 8);
    short8 C1 = *(const short8*)(xmb + (size_t)p * 64 + 32 + q * 8);
    #pragma unroll
    for (int t = 0; t < 9; t++) {
        short8 A0 = *(const short8*)(Wqk + (16 * t + m) * 64 + q * 8);
        short8 A1 = *(const short8*)(Wqk + (16 * t + m) * 64 + 32 + q * 8);
        f32x4 z = {0.f, 0.f, 0.f, 0.f};
        f32x4 D = __builtin_amdgcn_mfma_f32_16x16x32_bf16(A0, C0, z, 0, 0, 0);
        D = __builtin_amdgcn_mfma_f32_16x16x32_bf16(A1, C1, D, 0, 0, 0);
        #pragma unroll
        for (int g = 0; g < 4; g++) {
            int co = 16 * t + 4 * q + g;
            qkvr[(b * 144 + co) * HW + hw] = D[g];
        }
    }
}

// ---------------- depthwise/grouped 3x3: 4 px/thread float4. grid (16, 216) ----------------
__global__ void __launch_bounds__(256) k_dw(const float* __restrict__ t1, const float* __restrict__ t2,
                     const float* __restrict__ xn, const float* __restrict__ wts,
                     float* __restrict__ x1g, float* __restrict__ uf, float* __restrict__ araw) {
    int y = blockIdx.y;
    int pbase = blockIdx.x * 1024 + threadIdx.x * 4;
    int b = pbase >> 12, hw = pbase & 4095, h = hw >> 6, w0 = hw & 63;

    if (y < 192) {
        int c = (y < 96) ? y : y - 96;
        const float* base = (y < 96) ? t1 : t2;
        const float* wk = wts + ((y < 96) ? W_KDW2 : W_KC1B) + c * 9;
        const float* plane = base + (b * HID + c) * HW;

        float a0 = 0.f, a1 = 0.f, a2 = 0.f, a3 = 0.f;
        #pragma unroll
        for (int ki = 0; ki < 3; ki++) {
            int hh = h + ki - 1;
            if ((unsigned)hh < 64u) {
                const float* row = plane + hh * 64 + w0;
                float4 mm = *(const float4*)row;
                float lf = (w0 > 0) ? row[-1] : 0.f;
                float rt = (w0 < 60) ? row[4] : 0.f;
                float k0 = wk[ki * 3], k1 = wk[ki * 3 + 1], k2 = wk[ki * 3 + 2];
                a0 += k0 * lf   + k1 * mm.x + k2 * mm.y;
                a1 += k0 * mm.x + k1 * mm.y + k2 * mm.z;
                a2 += k0 * mm.y + k1 * mm.z + k2 * mm.w;
                a3 += k0 * mm.z + k1 * mm.w + k2 * rt;
            }
        }
        int idx = (b * HID + c) * HW + hw;
        if (y < 96) {
            float4 g;
            g.x = 0.5f * a0 * (1.f + erff(a0 * 0.70710678118654752f));
            g.y = 0.5f * a1 * (1.f + erff(a1 * 0.70710678118654752f));
            g.z = 0.5f * a2 * (1.f + erff(a2 * 0.70710678118654752f));
            g.w = 0.5f * a3 * (1.f + erff(a3 * 0.70710678118654752f));
            *(float4*)(x1g + idx) = g;
        } else {
            float4 o; o.x = a0; o.y = a1; o.z = a2; o.w = a3;
            *(float4*)(uf + idx) = o;
        }
    } else {
        int o = y - 192;
        float bias = wts[W_C2AB + o];
        float a0 = bias, a1 = bias, a2 = bias, a3 = bias;
        #pragma unroll
        for (int ic = 0; ic < 2; ic++) {
            const float* plane = xn + (b * Cc + 2 * o + ic) * HW;
            const float* wk = wts + W_C2AW + (o * 2 + ic) * 9;
            #pragma unroll
            for (int ki = 0; ki < 3; ki++) {
                int hh = h + ki - 1;
                if ((unsigned)hh < 64u) {
                    const float* row = plane + hh * 64 + w0;
                    float4 mm = *(const float4*)row;
                    float lf = (w0 > 0) ? row[-1] : 0.f;
                    float rt = (w0 < 60) ? row[4] : 0.f;
                    float k0 = wk[ki * 3], k1 = wk[ki * 3 + 1], k2 = wk[ki * 3 + 2];
                    a0 += k0 * lf   + k1 * mm.x + k2 * mm.y;
                    a1 += k0 * mm.x + k1 * mm.y + k2 * mm.z;
                    a2 += k0 * mm.y + k1 * mm.z + k2 * mm.w;
                    a3 += k0 * mm.z + k1 * mm.w + k2 * rt;
                }
            }
        }
        float4 out; out.x = a0; out.y = a1; out.z = a2; out.w = a3;
        *(float4*)(araw + (b * INTERC + o) * HW + hw) = out;
    }
}

// ---------------- att = attgamma * c2b(SimpleGate(araw)) + attn_t -> bf16 [p][32]. grid 64 x 256 ----------------
__global__ void __launch_bounds__(256) k_att(const float* __restrict__ araw, const float* __restrict__ attn_t,
                     const float* __restrict__ wts, ushortT* __restrict__ att_bf) {
    int p = blockIdx.x * 256 + threadIdx.x;
    int b = p >> 12, hw = p & 4095;
    const float* ab = araw + b * INTERC * HW + hw;
    float sg[12];
    #pragma unroll
    for (int i = 0; i < 12; i++) sg[i] = ab[i * HW] * ab[(12 + i) * HW];
    const float* ct = attn_t + (size_t)p * 32;
    uint32_t packed[16];
    #pragma unroll
    for (int nq = 0; nq < 16; nq++) {
        float v2[2];
        #pragma unroll
        for (int u = 0; u < 2; u++) {
            int n = nq * 2 + u;
            float a = wts[W_C2BB + n];
            #pragma unroll
            for (int c = 0; c < 12; c++) a += wts[W_C2BW + n * 12 + c] * sg[c];
            v2[u] = wts[W_ATTG + n] * a + ct[n];
        }
        packed[nq] = (uint32_t)f2b(v2[0]) | ((uint32_t)f2b(v2[1]) << 16);
    }
    uint4* dst = (uint4*)(att_bf + (size_t)p * 32);
    #pragma unroll
    for (int q = 0; q < 4; q++) {
        uint4 v; v.x = packed[q*4]; v.y = packed[q*4+1]; v.z = packed[q*4+2]; v.w = packed[q*4+3];
        dst[q] = v;
    }
}

// ---------------- KBA core via MFMA -> h_bf [p][96] bf16. grid (64,24) x 256 ----------------
__global__ void __launch_bounds__(256) k_kba(const ushortT* __restrict__ att_bf, const float* __restrict__ uf,
                     const float* __restrict__ x1g, const ushortT* __restrict__ Wt,
                     const float* __restrict__ wts, ushortT* __restrict__ h_bf) {
    int wave = threadIdx.x >> 6, lane = threadIdx.x & 63;
    int m = lane & 15, q = lane >> 4;
    int gr = blockIdx.y;

    short8 A[10];
    const ushortT* wtg = Wt + gr * 160 * 32;
    #pragma unroll
    for (int t = 0; t < 10; t++)
        A[t] = *(const short8*)(wtg + (16 * t + m) * 32 + q * 8);

    for (int tile = 0; tile < 4; tile++) {
        int p = blockIdx.x * 256 + wave * 64 + tile * 16 + m;
        int b = p >> 12, hw = p & 4095, h = hw >> 6, w = hw & 63;

        short8 Bf = *(const short8*)(att_bf + (size_t)p * 32 + q * 8);

        f32x4 D[10];
        #pragma unroll
        for (int t = 0; t < 10; t++) {
            f32x4 z = {0.f, 0.f, 0.f, 0.f};
            D[t] = __builtin_amdgcn_mfma_f32_16x16x32_bf16(A[t], Bf, z, 0, 0, 0);
        }

        float s0 = 0.f, s1 = 0.f, s2 = 0.f, s3 = 0.f;
        #pragma unroll
        for (int t = 0; t < 9; t++) {
            int j = 4 * t + q;
            int ci = j / 9;
            int kk = j - 9 * ci;
            int ki = kk / 3, kj = kk - 3 * ki;
            int hh = h + ki - 1, ww = w + kj - 1;
            float tap = 0.f;
            if ((unsigned)hh < 64u && (unsigned)ww < 64u)
                tap = uf[(b * HID + gr * 4 + ci) * HW + hh * 64 + ww];
            s0 += D[t][0] * tap;
            s1 += D[t][1] * tap;
            s2 += D[t][2] * tap;
            s3 += D[t][3] * tap;
        }
        s0 += D[9][0]; s1 += D[9][1]; s2 += D[9][2]; s3 += D[9][3];

        s0 += __shfl_xor(s0, 16); s0 += __shfl_xor(s0, 32);
        s1 += __shfl_xor(s1, 16); s1 += __shfl_xor(s1, 32);
        s2 += __shfl_xor(s2, 16); s2 += __shfl_xor(s2, 32);
        s3 += __shfl_xor(s3, 16); s3 += __shfl_xor(s3, 32);

        float sel = (q == 0) ? s0 : ((q == 1) ? s1 : ((q == 2) ? s2 : s3));
        int ch = gr * 4 + q;
        int idx = (b * HID + ch) * HW + hw;
        float x2 = sel * wts[W_GA1 + ch] + uf[idx];
        float hv = x1g[idx] * x2;
        h_bf[(size_t)p * 96 + ch] = f2b(hv);
    }
}

// ---------------- qkv depthwise 3x3: 4 px/thread float4. grid (16, 144) ----------------
__global__ void __launch_bounds__(256) k_qkvdw(const float* __restrict__ qkvr, const float* __restrict__ wts,
                        float* __restrict__ qkv) {
    int ch = blockIdx.y;
    const float* wk = wts + W_QKVDW + ch * 9;
    int pbase = blockIdx.x * 1024 + threadIdx.x * 4;
    int b = pbase >> 12, hw = pbase & 4095, h = hw >> 6, w0 = hw & 63;
    const float* plane = qkvr + (b * 144 + ch) * HW;

    float a0 = 0.f, a1 = 0.f, a2 = 0.f, a3 = 0.f;
    #pragma unroll
    for (int ki = 0; ki < 3; ki++) {
        int hh = h + ki - 1;
        if ((unsigned)hh < 64u) {
            const float* row = plane + hh * 64 + w0;
            float4 mm = *(const float4*)row;
            float lf = (w0 > 0) ? row[-1] : 0.f;
            float rt = (w0 < 60) ? row[4] : 0.f;
            float k0 = wk[ki * 3], k1 = wk[ki * 3 + 1], k2 = wk[ki * 3 + 2];
            a0 += k0 * lf   + k1 * mm.x + k2 * mm.y;
            a1 += k0 * mm.x + k1 * mm.y + k2 * mm.z;
            a2 += k0 * mm.y + k1 * mm.z + k2 * mm.w;
            a3 += k0 * mm.z + k1 * mm.w + k2 * rt;
        }
    }
    float4 o; o.x = a0; o.y = a1; o.z = a2; o.w = a3;
    *(float4*)(qkv + (b * 144 + ch) * HW + hw) = o;
}

// ---------------- smat1: partials + last-block finalize (softmax S + ca1/ca2). grid (32, 16) x 256 ----------------
__global__ void k_smat1(const float* __restrict__ qkv, float* __restrict__ Sp,
                        const float* __restrict__ gap, const float* __restrict__ wts,
                        float* __restrict__ S, float* __restrict__ ca1,
                        float* __restrict__ ca2, unsigned* __restrict__ cnt) {
    int bh = blockIdx.x, chunk = blockIdx.y;
    int b = bh / HEADS, hd = bh % HEADS;
    const float* qb = qkv + (b * 144 + hd * CPH) * HW;
    const float* kb = qkv + (b * 144 + 48 + hd * CPH) * HW;
    int px = chunk * 256 + threadIdx.x;
    float qv[CPH], kv[CPH];
    #pragma unroll
    for (int c = 0; c < CPH; c++) { qv[c] = qb[c * HW + px]; kv[c] = kb[c * HW + px]; }
    float acc[48];
    #pragma unroll
    for (int c = 0; c < CPH; c++) {
        #pragma unroll
        for (int d = 0; d < CPH; d++) acc[c * CPH + d] = qv[c] * kv[d];
        acc[36 + c] = qv[c] * qv[c];
        acc[42 + c] = kv[c] * kv[c];
    }
    __shared__ float red[48 * 4];
    int lane = threadIdx.x & 63, wv = threadIdx.x >> 6;
    #pragma unroll
    for (int t = 0; t < 48; t++) {
        float v = acc[t];
        #pragma unroll
        for (int o = 32; o > 0; o >>= 1) v += __shfl_down(v, o);
        if (lane == 0) red[t * 4 + wv] = v;
    }
    __syncthreads();
    if (threadIdx.x < 48)
        Sp[(bh * 16 + chunk) * 48 + threadIdx.x] =
            red[threadIdx.x * 4] + red[threadIdx.x * 4 + 1] +
            red[threadIdx.x * 4 + 2] + red[threadIdx.x * 4 + 3];
    // ---- last-block finalize ----
    __syncthreads();
    __shared__ unsigned lastFlag;
    if (threadIdx.x == 0) {
        __threadfence();
        lastFlag = (atomicAdd(cnt, 1u) == 511u) ? 1u : 0u;
    }
    __syncthreads();
    if (lastFlag == 0) return;
    __threadfence();
    __shared__ float sm[1536];
    const volatile float* Sv = Sp;
    for (int s = threadIdx.x; s < 1536; s += 256) {
        int sb = s / 48, k = s % 48;
        float v = 0.f;
        #pragma unroll
        for (int ch = 0; ch < 16; ch++) v += Sv[(sb * 16 + ch) * 48 + k];
        sm[s] = v;
    }
    __syncthreads();
    int t = threadIdx.x;
    if (t < 192) {
        int sbh = t / 6, c = t % 6;
        int hd2 = sbh % 8;
        const float* base = sm + sbh * 48;
        float rqv = 1.f / fmaxf(sqrtf(base[36 + c]), 1e-12f);
        float tmp = wts[W_TEMP + hd2];
        float row[CPH];
        #pragma unroll
        for (int d = 0; d < CPH; d++) {
            float rkv = 1.f / fmaxf(sqrtf(base[42 + d]), 1e-12f);
            row[d] = base[c * CPH + d] * rqv * rkv * tmp;
        }
        float mx = row[0];
        #pragma unroll
        for (int d = 1; d < CPH; d++) mx = fmaxf(mx, row[d]);
        float sum = 0.f;
        #pragma unroll
        for (int d = 0; d < CPH; d++) { row[d] = expf(row[d] - mx); sum += row[d]; }
        float inv = 1.f / sum;
        #pragma unroll
        for (int d = 0; d < CPH; d++) S[sbh * 36 + c * CPH + d] = row[d] * inv;
    }
    for (int e = t; e < 384; e += 256) {
        int which = e / 192, r = e % 192;
        int b2 = r / 48, co = r % 48;
        const float* g = gap + b2 * Cc;
        float sacc = wts[(which ? W_CA2B : W_CA1B) + co];
        #pragma unroll
        for (int c = 0; c < Cc; c++)
            sacc += wts[(which ? W_CA2W : W_CA1W) + co * Cc + c] * g[c];
        (which ? ca2 : ca1)[b2 * Cc + co] = sacc;
    }
}

// ---------------- finalm: kproj-MFMA + S@v + mproj-MFMA + residual epilogue. grid 256 x 256 ----------------
__global__ void __launch_bounds__(256) k_finalm(const void* __restrict__ x, const uint32_t* __restrict__ n1w_raw,
                        const ushortT* __restrict__ h_bf, const ushortT* __restrict__ Wkp,
                        const ushortT* __restrict__ Wmp, const float* __restrict__ qkv,
                        const float* __restrict__ S, const float* __restrict__ ca1,
                        const float* __restrict__ ca2, void* __restrict__ out) {
    int fl = dtype_bf16(n1w_raw);
    int wave = threadIdx.x >> 6, lane = threadIdx.x & 63;
    int m = lane & 15, q = lane >> 4;
    int p = blockIdx.x * 64 + wave * 16 + m;
    int b = p >> 12, hw = p & 4095;

    __shared__ float S_l[288];
    __shared__ float caL[96];
    for (int i = threadIdx.x; i < 288; i += 256) S_l[i] = S[b * 288 + i];
    for (int i = threadIdx.x; i < 96; i += 256)
        caL[i] = (i < 48) ? ca1[b * 48 + i] : ca2[b * 48 + (i - 48)];
    __syncthreads();

    // kproj: D1 = Wkp @ h_bf[p]
    short8 H0 = *(const short8*)(h_bf + (size_t)p * 96 + q * 8);
    short8 H1 = *(const short8*)(h_bf + (size_t)p * 96 + 32 + q * 8);
    short8 H2 = *(const short8*)(h_bf + (size_t)p * 96 + 64 + q * 8);
    f32x4 Dk[3];
    #pragma unroll
    for (int t = 0; t < 3; t++) {
        short8 A0 = *(const short8*)(Wkp + (16 * t + m) * 96 + q * 8);
        short8 A1 = *(const short8*)(Wkp + (16 * t + m) * 96 + 32 + q * 8);
        short8 A2 = *(const short8*)(Wkp + (16 * t + m) * 96 + 64 + q * 8);
        f32x4 z = {0.f, 0.f, 0.f, 0.f};
        f32x4 D = __builtin_amdgcn_mfma_f32_16x16x32_bf16(A0, H0, z, 0, 0, 0);
        D = __builtin_amdgcn_mfma_f32_16x16x32_bf16(A1, H1, D, 0, 0, 0);
        Dk[t] = __builtin_amdgcn_mfma_f32_16x16x32_bf16(A2, H2, D, 0, 0, 0);
    }

    // mdta B-fragments via S@v for this pixel
    const float* vbase = qkv + (b * 144 + 96) * HW + hw;
    short8 Bm0, Bm1;
    #pragma unroll
    for (int jj = 0; jj < 8; jj++) {
        int c0 = q * 8 + jj;              // 0..31, always valid
        int hd0 = c0 / 6, cc0 = c0 - 6 * hd0;
        float a = 0.f;
        #pragma unroll
        for (int d = 0; d < CPH; d++)
            a += S_l[hd0 * 36 + cc0 * 6 + d] * vbase[(hd0 * 6 + d) * HW];
        Bm0[jj] = (short)f2b(a);
        int c1 = 32 + q * 8 + jj;         // 32..63, valid if < 48
        float bv = 0.f;
        if (c1 < 48) {
            int hd1 = c1 / 6, cc1 = c1 - 6 * hd1;
            #pragma unroll
            for (int d = 0; d < CPH; d++)
                bv += S_l[hd1 * 36 + cc1 * 6 + d] * vbase[(hd1 * 6 + d) * HW];
        }
        Bm1[jj] = (short)f2b(bv);
    }

    // mproj + epilogue
    #pragma unroll
    for (int t = 0; t < 3; t++) {
        short8 A0 = *(const short8*)(Wmp + (16 * t + m) * 64 + q * 8);
        short8 A1 = *(const short8*)(Wmp + (16 * t + m) * 64 + 32 + q * 8);
        f32x4 z = {0.f, 0.f, 0.f, 0.f};
        f32x4 D = __builtin_amdgcn_mfma_f32_16x16x32_bf16(A0, Bm0, z, 0, 0, 0);
        D = __builtin_amdgcn_mfma_f32_16x16x32_bf16(A1, Bm1, D, 0, 0, 0);
        #pragma unroll
        for (int g = 0; g < 4; g++) {
            int co = 16 * t + 4 * q + g;
            int idx = (b * Cc + co) * HW + hw;
            float xv = fl ? b2f(((const ushortT*)x)[idx]) : ((const float*)x)[idx];
            float res = xv + Dk[t][g] * caL[co] + D[g] * caL[48 + co];
            if (fl) ((ushortT*)out)[idx] = f2b(res);
            else    ((float*)out)[idx] = res;
        }
    }
}

// ---------------- host launch ----------------
extern "C" void kernel_launch(void* const* d_in, const int* in_sizes, int n_in,
                              void* d_out, int out_size, void* d_ws, size_t ws_size,
                              hipStream_t stream) {
    float* ws_f = (float*)d_ws;

    float* xn    = ws_f + FXN;
    float* bufA  = ws_f + FA;     // t1 -> Sp
    float* bufB  = ws_f + FB;     // t2
    float* bufC  = ws_f + FC;     // x1g -> qkv (spans C+D)
    float* bufD  = ws_f + FD;     // uf
    float* araw  = ws_f + FARAW;
    float* attn_t= ws_f + FATT;
    float* gap   = ws_f + FGAP;
    float* ca1   = ws_f + FCA1;
    float* ca2   = ws_f + FCA2;
    float* Smat  = ws_f + FS;
    float* wts   = ws_f + FW;
    ushortT* att_bf  = (ushortT*)(ws_f + FATTB);
    ushortT* Wt      = (ushortT*)(ws_f + FWT);
    ushortT* xnb     = (ushortT*)(ws_f + FXNB);
    ushortT* xmb     = (ushortT*)(ws_f + FXMB);
    ushortT* h_bf    = (ushortT*)(ws_f + FHBF);
    ushortT* Wpw     = (ushortT*)(ws_f + FWPW);
    ushortT* Wqk     = (ushortT*)(ws_f + FWQK);
    ushortT* Wkp     = (ushortT*)(ws_f + FWKP);
    ushortT* Wmp     = (ushortT*)(ws_f + FWMP);
    unsigned* cnt    = (unsigned*)(ws_f + FCNT);
    float* qkvr      = ws_f + FQKVR;

    float* qkv  = bufC;
    float* Sp   = bufA;
    const uint32_t* n1w_raw = (const uint32_t*)d_in[1];

    static const int wsizes[27] = {48,48,48,48,4608,864,4608,864,4608,432,24,384,32,
                                   1536,32,110592,3072,32,96,8,6912,1296,2304,2304,48,2304,48};
    static const int woffs[27] = {W_N1W,W_N1B,W_N2W,W_N2B,W_KDW1,W_KDW2,W_KC1A,W_KC1B,
                                  W_KPROJ,W_C2AW,W_C2AB,W_C2BW,W_C2BB,W_C211W,W_C211B,
                                  W_KW,W_KB,W_ATTG,W_GA1,W_TEMP,W_QKVW,W_QKVDW,W_MPROJ,
                                  W_CA1W,W_CA1B,W_CA2W,W_CA2B};
    ConvPack cp;
    for (int i = 0; i < 27; i++) {
        cp.src[i] = d_in[i + 1];
        cp.dstoff[i] = woffs[i];
        cp.n[i] = wsizes[i];
    }
    RawW rw;
    rw.kdw1 = d_in[5]; rw.kc1a = d_in[7]; rw.c211w = d_in[14]; rw.qkvw = d_in[21];
    rw.kproj = d_in[9]; rw.mproj = d_in[23]; rw.kw = d_in[16]; rw.kb = d_in[17];
    rw.n1w = d_in[1]; rw.n1b = d_in[2]; rw.n2w = d_in[3]; rw.n2b = d_in[4];

    k_prep<<<dim3(64, 34), 256, 0, stream>>>(cp, rw, wts, Wt, Wpw, Wqk, Wkp, Wmp,
                                             d_in[0], gap, xn, xnb, xmb, cnt, n1w_raw);
    k_pw1m<<<dim3(256), 256, 0, stream>>>(xnb, xmb, Wpw, Wqk, wts, bufA, bufB, attn_t, qkvr);
    k_dw<<<dim3(16, 216), 256, 0, stream>>>(bufA, bufB, xn, wts, bufC, bufD, araw);
    k_att<<<dim3(64), 256, 0, stream>>>(araw, attn_t, wts, att_bf);
    k_kba<<<dim3(64, 24), 256, 0, stream>>>(att_bf, bufD, bufC, Wt, wts, h_bf);
    k_qkvdw<<<dim3(16, 144), 256, 0, stream>>>(qkvr, wts, qkv);
    k_smat1<<<dim3(32, 16), 256, 0, stream>>>(qkv, Sp, gap, wts, Smat, ca1, ca2, cnt);
    k_finalm<<<dim3(256), 256, 0, stream>>>(d_in[0], n1w_raw, h_bf, Wkp, Wmp,
                                            qkv, Smat, ca1, ca2, d_out);
}

// Round 9
// 232.869 us; speedup vs baseline: 1.1608x; 1.1608x over previous
//
#include <hip/hip_runtime.h>
#include <hip/hip_bf16.h>
#include <cstdint>

typedef unsigned short ushortT;
typedef __attribute__((ext_vector_type(8))) short short8;
typedef __attribute__((ext_vector_type(4))) float f32x4;

// ---------------- problem constants ----------------
static constexpr int Bn = 4, Cc = 48, Hh = 64, Wd = 64, HW = 4096;
static constexpr int HID = 96, NSET = 32, INTERC = 24, HEADS = 8, CPH = 6;

// ---------------- ws layout (float offsets) ----------------
static constexpr int FXN   = 0;         // 786432  xn fp32 planar (c2a halo use)
static constexpr int FA    = 786432;    // 1572864 t1 ; later Sp
static constexpr int FB    = 2359296;   // 1572864 t2
static constexpr int FC    = 3932160;   // 1572864 x1g -> qkv (spans C+D)
static constexpr int FD    = 5505024;   // 1572864 uf
static constexpr int FARAW = 7077888;   // 393216
static constexpr int FATT  = 7471104;   // 524288  attn_t fp32 [p][32]
static constexpr int FGAP  = 8781824;   // 192
static constexpr int FCA1  = 8782016;   // 192
static constexpr int FCA2  = 8782208;   // 192
static constexpr int FS    = 8782400;   // 1152 Smat
static constexpr int FW    = 8783552;   // 147200 fp32 weights
static constexpr int FATTB = 8930752;   // 262144 fl: att_bf [p][32] bf16
static constexpr int FWT   = 9192896;   // 61440 fl: Wt bf16 (KBA)
static constexpr int FXNB  = 9254336;   // 524288 fl: xnb [p][64] bf16
static constexpr int FXMB  = 9778624;   // 524288 fl: xmb [p][64] bf16
static constexpr int FHBF  = 10302912;  // 786432 fl: h_bf [p][96] bf16
static constexpr int FWPW  = 11089344;  // 7168 fl: Wpw [224][64] bf16
static constexpr int FWQK  = 11096512;  // 4608 fl: Wqk [144][64] bf16
static constexpr int FWKP  = 11101120;  // 2304 fl: Wkp [48][96] bf16
static constexpr int FWMP  = 11103424;  // 1536 fl: Wmp [48][64] bf16
static constexpr int FQKVR = 11105024;  // 2359296 fl: qkvr planar
// total = 13464320 floats = 53.9 MB

// ---- weight offsets inside FW ----
static constexpr int W_N1W=0, W_N1B=48, W_N2W=96, W_N2B=144;
static constexpr int W_KDW1=192, W_KDW2=4800, W_KC1A=5664, W_KC1B=10272;
static constexpr int W_KPROJ=11136, W_C2AW=15744, W_C2AB=16176;
static constexpr int W_C2BW=16200, W_C2BB=16584, W_C211W=16616, W_C211B=18152;
static constexpr int W_KW=18184, W_KB=128776, W_ATTG=131848, W_GA1=131880;
static constexpr int W_TEMP=131976, W_QKVW=131984, W_QKVDW=138896, W_MPROJ=140192;
static constexpr int W_CA1W=142496, W_CA1B=144800, W_CA2W=144848, W_CA2B=147152;

__device__ __forceinline__ float b2f(ushortT u) {
    union { uint32_t i; float f; } v; v.i = ((uint32_t)u) << 16; return v.f;
}
__device__ __forceinline__ ushortT f2b(float f) {
    union { float f; uint32_t i; } v; v.f = f;
    uint32_t i = v.i;
    uint32_t lsb = (i >> 16) & 1u;
    i += 0x7fffu + lsb;
    return (ushortT)(i >> 16);
}
__device__ __forceinline__ int dtype_bf16(const uint32_t* n1w_raw) {
    return n1w_raw[0] == 0x3F803F80u;
}
__device__ __forceinline__ ushortT raw_bf(const void* p, int idx, int fl) {
    return fl ? ((const ushortT*)p)[idx] : f2b(((const float*)p)[idx]);
}
__device__ __forceinline__ float raw_f(const void* p, int idx, int fl) {
    return fl ? b2f(((const ushortT*)p)[idx]) : ((const float*)p)[idx];
}

// ---------------- prep: convert + all bf16 weight matrices + gap + LN ----------------
struct ConvPack {
    const void* src[27];
    int dstoff[27];
    int n[27];
};
struct RawW {
    const void* kdw1; const void* kc1a; const void* c211w; const void* qkvw;
    const void* kproj; const void* mproj; const void* kw; const void* kb;
    const void* n1w; const void* n1b; const void* n2w; const void* n2b;
};

__global__ void k_prep(ConvPack p, RawW rw, float* __restrict__ dst,
                       ushortT* __restrict__ Wt, ushortT* __restrict__ Wpw,
                       ushortT* __restrict__ Wqk, ushortT* __restrict__ Wkp,
                       ushortT* __restrict__ Wmp,
                       const void* __restrict__ x, float* __restrict__ gap,
                       float* __restrict__ xn, ushortT* __restrict__ xnb,
                       ushortT* __restrict__ xmb,
                       const uint32_t* __restrict__ n1w_raw) {
    int fl = dtype_bf16(n1w_raw);
    int y = blockIdx.y;
    if (y < 27) {
        int n = p.n[y];
        for (int i = blockIdx.x * 256 + threadIdx.x; i < n; i += 64 * 256) {
            dst[p.dstoff[y] + i] = raw_f(p.src[y], i, fl);
        }
    } else if (y == 27) {
        for (int u = blockIdx.x * 256 + threadIdx.x; u < 24 * 160 * 32; u += 64 * 256) {
            int n = u & 31;
            int rest = u >> 5;
            int r = rest % 160;
            int gr = rest / 160;
            ushortT out;
            if (r < 144) {
                int j = r >> 2, i = r & 3;
                out = raw_bf(rw.kw, n * 3456 + gr * 144 + i * 36 + j, fl);
            } else if (r < 148) {
                out = raw_bf(rw.kb, n * HID + gr * 4 + (r - 144), fl);
            } else out = 0;
            Wt[u] = out;
        }
    } else if (y == 28) {
        for (int u = blockIdx.x * 256 + threadIdx.x; u < 224 * 64; u += 64 * 256) {
            int co = u >> 6, c = u & 63;
            ushortT v = 0;
            if (c < 48) {
                if (co < 96)       v = raw_bf(rw.kdw1,  co * 48 + c, fl);
                else if (co < 192) v = raw_bf(rw.kc1a,  (co - 96) * 48 + c, fl);
                else               v = raw_bf(rw.c211w, (co - 192) * 48 + c, fl);
            }
            Wpw[u] = v;
        }
    } else if (y == 29) {
        for (int u = blockIdx.x * 256 + threadIdx.x; u < 144 * 64; u += 64 * 256) {
            int co = u >> 6, c = u & 63;
            Wqk[u] = (c < 48) ? raw_bf(rw.qkvw, co * 48 + c, fl) : (ushortT)0;
        }
    } else if (y == 30) {
        for (int u = blockIdx.x * 256 + threadIdx.x; u < 48 * 96; u += 64 * 256) {
            int co = u / 96, c = u % 96;
            Wkp[u] = raw_bf(rw.kproj, co * 96 + c, fl);
        }
    } else if (y == 31) {
        for (int u = blockIdx.x * 256 + threadIdx.x; u < 48 * 64; u += 64 * 256) {
            int co = u >> 6, c = u & 63;
            Wmp[u] = (c < 48) ? raw_bf(rw.mproj, co * 48 + c, fl) : (ushortT)0;
        }
    } else if (y == 32) {
        __shared__ float red[4];
        for (int bc = blockIdx.x; bc < Bn * Cc; bc += 64) {
            float s = 0.f;
            if (fl) {
                const ushortT* xb = (const ushortT*)x + bc * HW;
                for (int i = threadIdx.x; i < HW; i += 256) s += b2f(xb[i]);
            } else {
                const float* xb = (const float*)x + bc * HW;
                for (int i = threadIdx.x; i < HW; i += 256) s += xb[i];
            }
            #pragma unroll
            for (int o = 32; o > 0; o >>= 1) s += __shfl_down(s, o);
            int lane = threadIdx.x & 63, wv = threadIdx.x >> 6;
            if (lane == 0) red[wv] = s;
            __syncthreads();
            if (threadIdx.x == 0)
                gap[bc] = (red[0] + red[1] + red[2] + red[3]) * (1.f / HW);
            __syncthreads();
        }
    } else {
        // LN1 + LN2 from raw weights
        int pp = blockIdx.x * 256 + threadIdx.x;
        int b = pp >> 12, hw = pp & 4095;
        float xr[Cc];
        if (fl) {
            const ushortT* xb = (const ushortT*)x + b * Cc * HW + hw;
            #pragma unroll
            for (int c = 0; c < Cc; c++) xr[c] = b2f(xb[c * HW]);
        } else {
            const float* xb = (const float*)x + b * Cc * HW + hw;
            #pragma unroll
            for (int c = 0; c < Cc; c++) xr[c] = xb[c * HW];
        }
        float s = 0.f, ss = 0.f;
        #pragma unroll
        for (int c = 0; c < Cc; c++) { s += xr[c]; ss += xr[c] * xr[c]; }
        float mu = s * (1.f / Cc);
        float var = ss * (1.f / Cc) - mu * mu;
        float r = rsqrtf(var + 1e-6f);
        uint32_t pn[32], pm[32];
        #pragma unroll
        for (int i = 0; i < 24; i++) {
            float y0 = (xr[2 * i] - mu) * r, y1 = (xr[2 * i + 1] - mu) * r;
            float n0 = raw_f(rw.n1w, 2 * i, fl) * y0 + raw_f(rw.n1b, 2 * i, fl);
            float n1 = raw_f(rw.n1w, 2 * i + 1, fl) * y1 + raw_f(rw.n1b, 2 * i + 1, fl);
            float m0 = raw_f(rw.n2w, 2 * i, fl) * y0 + raw_f(rw.n2b, 2 * i, fl);
            float m1 = raw_f(rw.n2w, 2 * i + 1, fl) * y1 + raw_f(rw.n2b, 2 * i + 1, fl);
            xn[(b * Cc + 2 * i) * HW + hw] = n0;
            xn[(b * Cc + 2 * i + 1) * HW + hw] = n1;
            pn[i] = (uint32_t)f2b(n0) | ((uint32_t)f2b(n1) << 16);
            pm[i] = (uint32_t)f2b(m0) | ((uint32_t)f2b(m1) << 16);
        }
        #pragma unroll
        for (int i = 24; i < 32; i++) { pn[i] = 0; pm[i] = 0; }
        uint4* dn = (uint4*)(xnb + (size_t)pp * 64);
        uint4* dm = (uint4*)(xmb + (size_t)pp * 64);
        #pragma unroll
        for (int qd = 0; qd < 8; qd++) {
            uint4 v; v.x = pn[qd*4]; v.y = pn[qd*4+1]; v.z = pn[qd*4+2]; v.w = pn[qd*4+3];
            dn[qd] = v;
            uint4 u; u.x = pm[qd*4]; u.y = pm[qd*4+1]; u.z = pm[qd*4+2]; u.w = pm[qd*4+3];
            dm[qd] = u;
        }
    }
}

// ---------------- pw1m: [224x48]@xnb -> t1,t2,attn_t  AND  [144x48]@xmb -> qkvr. grid 256 x 256 ----------------
__global__ void __launch_bounds__(256) k_pw1m(const ushortT* __restrict__ xnb, const ushortT* __restrict__ xmb,
                       const ushortT* __restrict__ Wpw, const ushortT* __restrict__ Wqk,
                       const float* __restrict__ wts, float* __restrict__ t1,
                       float* __restrict__ t2, float* __restrict__ attn_t,
                       float* __restrict__ qkvr) {
    int wave = threadIdx.x >> 6, lane = threadIdx.x & 63;
    int m = lane & 15, q = lane >> 4;
    int p = blockIdx.x * 64 + wave * 16 + m;
    int b = p >> 12, hw = p & 4095;
    short8 B0 = *(const short8*)(xnb + (size_t)p * 64 + q * 8);
    short8 B1 = *(const short8*)(xnb + (size_t)p * 64 + 32 + q * 8);
    #pragma unroll
    for (int t = 0; t < 14; t++) {
        short8 A0 = *(const short8*)(Wpw + (16 * t + m) * 64 + q * 8);
        short8 A1 = *(const short8*)(Wpw + (16 * t + m) * 64 + 32 + q * 8);
        f32x4 z = {0.f, 0.f, 0.f, 0.f};
        f32x4 D = __builtin_amdgcn_mfma_f32_16x16x32_bf16(A0, B0, z, 0, 0, 0);
        D = __builtin_amdgcn_mfma_f32_16x16x32_bf16(A1, B1, D, 0, 0, 0);
        #pragma unroll
        for (int g = 0; g < 4; g++) {
            int co = 16 * t + 4 * q + g;
            if (t < 6) t1[(b * HID + co) * HW + hw] = D[g];
            else if (t < 12) t2[(b * HID + (co - 96)) * HW + hw] = D[g];
            else {
                int n = co - 192;
                attn_t[(size_t)p * 32 + n] = D[g] + wts[W_C211B + n];
            }
        }
    }
    short8 C0 = *(const short8*)(xmb + (size_t)p * 64 + q * 8);
    short8 C1 = *(const short8*)(xmb + (size_t)p * 64 + 32 + q * 8);
    #pragma unroll
    for (int t = 0; t < 9; t++) {
        short8 A0 = *(const short8*)(Wqk + (16 * t + m) * 64 + q * 8);
        short8 A1 = *(const short8*)(Wqk + (16 * t + m) * 64 + 32 + q * 8);
        f32x4 z = {0.f, 0.f, 0.f, 0.f};
        f32x4 D = __builtin_amdgcn_mfma_f32_16x16x32_bf16(A0, C0, z, 0, 0, 0);
        D = __builtin_amdgcn_mfma_f32_16x16x32_bf16(A1, C1, D, 0, 0, 0);
        #pragma unroll
        for (int g = 0; g < 4; g++) {
            int co = 16 * t + 4 * q + g;
            qkvr[(b * 144 + co) * HW + hw] = D[g];
        }
    }
}

// ---------------- depthwise/grouped 3x3: 4 px/thread, float4 IO. grid (16, 216) ----------------
__global__ void __launch_bounds__(256) k_dw(const float* __restrict__ t1, const float* __restrict__ t2,
                     const float* __restrict__ xn, const float* __restrict__ wts,
                     float* __restrict__ x1g, float* __restrict__ uf, float* __restrict__ araw) {
    int y = blockIdx.y;
    int pbase = blockIdx.x * 1024 + threadIdx.x * 4;
    int b = pbase >> 12, hw = pbase & 4095, h = hw >> 6, w0 = hw & 63;

    if (y < 192) {
        int c = (y < 96) ? y : y - 96;
        const float* base = (y < 96) ? t1 : t2;
        const float* wk = wts + ((y < 96) ? W_KDW2 : W_KC1B) + c * 9;
        const float* plane = base + (b * HID + c) * HW;

        float a0 = 0.f, a1 = 0.f, a2 = 0.f, a3 = 0.f;
        #pragma unroll
        for (int ki = 0; ki < 3; ki++) {
            int hh = h + ki - 1;
            if ((unsigned)hh < 64u) {
                const float* row = plane + hh * 64 + w0;
                float4 mm = *(const float4*)row;
                float lf = (w0 > 0) ? row[-1] : 0.f;
                float rt = (w0 < 60) ? row[4] : 0.f;
                float k0 = wk[ki * 3], k1 = wk[ki * 3 + 1], k2 = wk[ki * 3 + 2];
                a0 += k0 * lf   + k1 * mm.x + k2 * mm.y;
                a1 += k0 * mm.x + k1 * mm.y + k2 * mm.z;
                a2 += k0 * mm.y + k1 * mm.z + k2 * mm.w;
                a3 += k0 * mm.z + k1 * mm.w + k2 * rt;
            }
        }
        int idx = (b * HID + c) * HW + hw;
        if (y < 96) {
            float4 g;
            g.x = 0.5f * a0 * (1.f + erff(a0 * 0.70710678118654752f));
            g.y = 0.5f * a1 * (1.f + erff(a1 * 0.70710678118654752f));
            g.z = 0.5f * a2 * (1.f + erff(a2 * 0.70710678118654752f));
            g.w = 0.5f * a3 * (1.f + erff(a3 * 0.70710678118654752f));
            *(float4*)(x1g + idx) = g;
        } else {
            float4 o; o.x = a0; o.y = a1; o.z = a2; o.w = a3;
            *(float4*)(uf + idx) = o;
        }
    } else {
        int o = y - 192;
        float bias = wts[W_C2AB + o];
        float a0 = bias, a1 = bias, a2 = bias, a3 = bias;
        #pragma unroll
        for (int ic = 0; ic < 2; ic++) {
            const float* plane = xn + (b * Cc + 2 * o + ic) * HW;
            const float* wk = wts + W_C2AW + (o * 2 + ic) * 9;
            #pragma unroll
            for (int ki = 0; ki < 3; ki++) {
                int hh = h + ki - 1;
                if ((unsigned)hh < 64u) {
                    const float* row = plane + hh * 64 + w0;
                    float4 mm = *(const float4*)row;
                    float lf = (w0 > 0) ? row[-1] : 0.f;
                    float rt = (w0 < 60) ? row[4] : 0.f;
                    float k0 = wk[ki * 3], k1 = wk[ki * 3 + 1], k2 = wk[ki * 3 + 2];
                    a0 += k0 * lf   + k1 * mm.x + k2 * mm.y;
                    a1 += k0 * mm.x + k1 * mm.y + k2 * mm.z;
                    a2 += k0 * mm.y + k1 * mm.z + k2 * mm.w;
                    a3 += k0 * mm.z + k1 * mm.w + k2 * rt;
                }
            }
        }
        float4 out; out.x = a0; out.y = a1; out.z = a2; out.w = a3;
        *(float4*)(araw + (b * INTERC + o) * HW + hw) = out;
    }
}

// ---------------- att = attgamma * c2b(SimpleGate(araw)) + attn_t -> bf16 [p][32]. grid 64 x 256 ----------------
__global__ void __launch_bounds__(256) k_att(const float* __restrict__ araw, const float* __restrict__ attn_t,
                     const float* __restrict__ wts, ushortT* __restrict__ att_bf) {
    int p = blockIdx.x * 256 + threadIdx.x;
    int b = p >> 12, hw = p & 4095;
    const float* ab = araw + b * INTERC * HW + hw;
    float sg[12];
    #pragma unroll
    for (int i = 0; i < 12; i++) sg[i] = ab[i * HW] * ab[(12 + i) * HW];
    const float* ct = attn_t + (size_t)p * 32;
    uint32_t packed[16];
    #pragma unroll
    for (int nq = 0; nq < 16; nq++) {
        float v2[2];
        #pragma unroll
        for (int u = 0; u < 2; u++) {
            int n = nq * 2 + u;
            float a = wts[W_C2BB + n];
            #pragma unroll
            for (int c = 0; c < 12; c++) a += wts[W_C2BW + n * 12 + c] * sg[c];
            v2[u] = wts[W_ATTG + n] * a + ct[n];
        }
        packed[nq] = (uint32_t)f2b(v2[0]) | ((uint32_t)f2b(v2[1]) << 16);
    }
    uint4* dst = (uint4*)(att_bf + (size_t)p * 32);
    #pragma unroll
    for (int q = 0; q < 4; q++) {
        uint4 v; v.x = packed[q*4]; v.y = packed[q*4+1]; v.z = packed[q*4+2]; v.w = packed[q*4+3];
        dst[q] = v;
    }
}

// ---------------- KBA core via MFMA -> h_bf [p][96] bf16. grid (64,24) x 256 ----------------
__global__ void __launch_bounds__(256) k_kba(const ushortT* __restrict__ att_bf, const float* __restrict__ uf,
                     const float* __restrict__ x1g, const ushortT* __restrict__ Wt,
                     const float* __restrict__ wts, ushortT* __restrict__ h_bf) {
    int wave = threadIdx.x >> 6, lane = threadIdx.x & 63;
    int m = lane & 15, q = lane >> 4;
    int gr = blockIdx.y;

    short8 A[10];
    const ushortT* wtg = Wt + gr * 160 * 32;
    #pragma unroll
    for (int t = 0; t < 10; t++)
        A[t] = *(const short8*)(wtg + (16 * t + m) * 32 + q * 8);

    for (int tile = 0; tile < 4; tile++) {
        int p = blockIdx.x * 256 + wave * 64 + tile * 16 + m;
        int b = p >> 12, hw = p & 4095, h = hw >> 6, w = hw & 63;

        short8 Bf = *(const short8*)(att_bf + (size_t)p * 32 + q * 8);

        f32x4 D[10];
        #pragma unroll
        for (int t = 0; t < 10; t++) {
            f32x4 z = {0.f, 0.f, 0.f, 0.f};
            D[t] = __builtin_amdgcn_mfma_f32_16x16x32_bf16(A[t], Bf, z, 0, 0, 0);
        }

        float s0 = 0.f, s1 = 0.f, s2 = 0.f, s3 = 0.f;
        #pragma unroll
        for (int t = 0; t < 9; t++) {
            int j = 4 * t + q;
            int ci = j / 9;
            int kk = j - 9 * ci;
            int ki = kk / 3, kj = kk - 3 * ki;
            int hh = h + ki - 1, ww = w + kj - 1;
            float tap = 0.f;
            if ((unsigned)hh < 64u && (unsigned)ww < 64u)
                tap = uf[(b * HID + gr * 4 + ci) * HW + hh * 64 + ww];
            s0 += D[t][0] * tap;
            s1 += D[t][1] * tap;
            s2 += D[t][2] * tap;
            s3 += D[t][3] * tap;
        }
        s0 += D[9][0]; s1 += D[9][1]; s2 += D[9][2]; s3 += D[9][3];

        s0 += __shfl_xor(s0, 16); s0 += __shfl_xor(s0, 32);
        s1 += __shfl_xor(s1, 16); s1 += __shfl_xor(s1, 32);
        s2 += __shfl_xor(s2, 16); s2 += __shfl_xor(s2, 32);
        s3 += __shfl_xor(s3, 16); s3 += __shfl_xor(s3, 32);

        float sel = (q == 0) ? s0 : ((q == 1) ? s1 : ((q == 2) ? s2 : s3));
        int ch = gr * 4 + q;
        int idx = (b * HID + ch) * HW + hw;
        float x2 = sel * wts[W_GA1 + ch] + uf[idx];
        float hv = x1g[idx] * x2;
        h_bf[(size_t)p * 96 + ch] = f2b(hv);
    }
}

// ---------------- qkv depthwise 3x3: 4 px/thread float4. grid (16, 144) ----------------
__global__ void __launch_bounds__(256) k_qkvdw(const float* __restrict__ qkvr, const float* __restrict__ wts,
                        float* __restrict__ qkv) {
    int ch = blockIdx.y;
    const float* wk = wts + W_QKVDW + ch * 9;
    int pbase = blockIdx.x * 1024 + threadIdx.x * 4;
    int b = pbase >> 12, hw = pbase & 4095, h = hw >> 6, w0 = hw & 63;
    const float* plane = qkvr + (b * 144 + ch) * HW;

    float a0 = 0.f, a1 = 0.f, a2 = 0.f, a3 = 0.f;
    #pragma unroll
    for (int ki = 0; ki < 3; ki++) {
        int hh = h + ki - 1;
        if ((unsigned)hh < 64u) {
            const float* row = plane + hh * 64 + w0;
            float4 mm = *(const float4*)row;
            float lf = (w0 > 0) ? row[-1] : 0.f;
            float rt = (w0 < 60) ? row[4] : 0.f;
            float k0 = wk[ki * 3], k1 = wk[ki * 3 + 1], k2 = wk[ki * 3 + 2];
            a0 += k0 * lf   + k1 * mm.x + k2 * mm.y;
            a1 += k0 * mm.x + k1 * mm.y + k2 * mm.z;
            a2 += k0 * mm.y + k1 * mm.z + k2 * mm.w;
            a3 += k0 * mm.z + k1 * mm.w + k2 * rt;
        }
    }
    float4 o; o.x = a0; o.y = a1; o.z = a2; o.w = a3;
    *(float4*)(qkv + (b * 144 + ch) * HW + hw) = o;
}

// ---------------- S partials + q/k norm partials: 4 px/thread, grid (32, 4) x 256 ----------------
__global__ void k_smat1(const float* __restrict__ qkv, float* __restrict__ Sp) {
    int bh = blockIdx.x, chunk = blockIdx.y;
    int b = bh / HEADS, hd = bh % HEADS;
    const float* qb = qkv + (b * 144 + hd * CPH) * HW;
    const float* kb = qkv + (b * 144 + 48 + hd * CPH) * HW;
    float acc[48];
    #pragma unroll
    for (int t = 0; t < 48; t++) acc[t] = 0.f;
    #pragma unroll
    for (int i = 0; i < 4; i++) {
        int px = chunk * 1024 + i * 256 + threadIdx.x;
        float qv[CPH], kv[CPH];
        #pragma unroll
        for (int c = 0; c < CPH; c++) { qv[c] = qb[c * HW + px]; kv[c] = kb[c * HW + px]; }
        #pragma unroll
        for (int c = 0; c < CPH; c++) {
            #pragma unroll
            for (int d = 0; d < CPH; d++) acc[c * CPH + d] += qv[c] * kv[d];
            acc[36 + c] += qv[c] * qv[c];
            acc[42 + c] += kv[c] * kv[c];
        }
    }
    __shared__ float red[48 * 4];
    int lane = threadIdx.x & 63, wv = threadIdx.x >> 6;
    #pragma unroll
    for (int t = 0; t < 48; t++) {
        float v = acc[t];
        #pragma unroll
        for (int o = 32; o > 0; o >>= 1) v += __shfl_down(v, o);
        if (lane == 0) red[t * 4 + wv] = v;
    }
    __syncthreads();
    if (threadIdx.x < 48)
        Sp[(bh * 4 + chunk) * 48 + threadIdx.x] =
            red[threadIdx.x * 4] + red[threadIdx.x * 4 + 1] +
            red[threadIdx.x * 4 + 2] + red[threadIdx.x * 4 + 3];
}

// ---------------- finalize softmax S (+ channel attention ca1/ca2). grid 32 x 64 ----------------
__global__ void k_smat2(const float* __restrict__ Sp, const float* __restrict__ gap,
                        const float* __restrict__ wts, float* __restrict__ S,
                        float* __restrict__ ca1, float* __restrict__ ca2) {
    int bh = blockIdx.x;
    int b = bh / HEADS, hd = bh % HEADS;
    int t = threadIdx.x;
    __shared__ float sm[48];
    if (t < 48) {
        float v = 0.f;
        #pragma unroll
        for (int ch = 0; ch < 4; ch++) v += Sp[(bh * 4 + ch) * 48 + t];
        sm[t] = v;
    }
    __syncthreads();
    if (t < CPH) {
        float rqv = 1.f / fmaxf(sqrtf(sm[36 + t]), 1e-12f);
        float tmp = wts[W_TEMP + hd];
        float row[CPH];
        #pragma unroll
        for (int d = 0; d < CPH; d++) {
            float rkv = 1.f / fmaxf(sqrtf(sm[42 + d]), 1e-12f);
            row[d] = sm[t * CPH + d] * rqv * rkv * tmp;
        }
        float mx = row[0];
        #pragma unroll
        for (int d = 1; d < CPH; d++) mx = fmaxf(mx, row[d]);
        float sum = 0.f;
        #pragma unroll
        for (int d = 0; d < CPH; d++) { row[d] = expf(row[d] - mx); sum += row[d]; }
        float inv = 1.f / sum;
        #pragma unroll
        for (int d = 0; d < CPH; d++) S[bh * 36 + t * CPH + d] = row[d] * inv;
    }
    if (t >= 52 && t < 64) {
        int idx = t - 52;
        int which = idx / 6, cc = idx % 6;
        int co = hd * CPH + cc;
        const float* g = gap + b * Cc;
        float sacc = wts[(which ? W_CA2B : W_CA1B) + co];
        #pragma unroll
        for (int c = 0; c < Cc; c++)
            sacc += wts[(which ? W_CA2W : W_CA1W) + co * Cc + c] * g[c];
        (which ? ca2 : ca1)[b * Cc + co] = sacc;
    }
}

// ---------------- finalm: kproj-MFMA + S@v + mproj-MFMA + residual epilogue. grid 256 x 256 ----------------
__global__ void __launch_bounds__(256) k_finalm(const void* __restrict__ x, const uint32_t* __restrict__ n1w_raw,
                        const ushortT* __restrict__ h_bf, const ushortT* __restrict__ Wkp,
                        const ushortT* __restrict__ Wmp, const float* __restrict__ qkv,
                        const float* __restrict__ S, const float* __restrict__ ca1,
                        const float* __restrict__ ca2, void* __restrict__ out) {
    int fl = dtype_bf16(n1w_raw);
    int wave = threadIdx.x >> 6, lane = threadIdx.x & 63;
    int m = lane & 15, q = lane >> 4;
    int p = blockIdx.x * 64 + wave * 16 + m;
    int b = p >> 12, hw = p & 4095;

    __shared__ float S_l[288];
    __shared__ float caL[96];
    for (int i = threadIdx.x; i < 288; i += 256) S_l[i] = S[b * 288 + i];
    for (int i = threadIdx.x; i < 96; i += 256)
        caL[i] = (i < 48) ? ca1[b * 48 + i] : ca2[b * 48 + (i - 48)];
    __syncthreads();

    // kproj: Dk = Wkp @ h_bf[p]
    short8 H0 = *(const short8*)(h_bf + (size_t)p * 96 + q * 8);
    short8 H1 = *(const short8*)(h_bf + (size_t)p * 96 + 32 + q * 8);
    short8 H2 = *(const short8*)(h_bf + (size_t)p * 96 + 64 + q * 8);
    f32x4 Dk[3];
    #pragma unroll
    for (int t = 0; t < 3; t++) {
        short8 A0 = *(const short8*)(Wkp + (16 * t + m) * 96 + q * 8);
        short8 A1 = *(const short8*)(Wkp + (16 * t + m) * 96 + 32 + q * 8);
        short8 A2 = *(const short8*)(Wkp + (16 * t + m) * 96 + 64 + q * 8);
        f32x4 z = {0.f, 0.f, 0.f, 0.f};
        f32x4 D = __builtin_amdgcn_mfma_f32_16x16x32_bf16(A0, H0, z, 0, 0, 0);
        D = __builtin_amdgcn_mfma_f32_16x16x32_bf16(A1, H1, D, 0, 0, 0);
        Dk[t] = __builtin_amdgcn_mfma_f32_16x16x32_bf16(A2, H2, D, 0, 0, 0);
    }

    // mdta B-fragments via S@v for this pixel
    const float* vbase = qkv + (b * 144 + 96) * HW + hw;
    short8 Bm0, Bm1;
    #pragma unroll
    for (int jj = 0; jj < 8; jj++) {
        int c0 = q * 8 + jj;
        int hd0 = c0 / 6, cc0 = c0 - 6 * hd0;
        float a = 0.f;
        #pragma unroll
        for (int d = 0; d < CPH; d++)
            a += S_l[hd0 * 36 + cc0 * 6 + d] * vbase[(hd0 * 6 + d) * HW];
        Bm0[jj] = (short)f2b(a);
        int c1 = 32 + q * 8 + jj;
        float bv = 0.f;
        if (c1 < 48) {
            int hd1 = c1 / 6, cc1 = c1 - 6 * hd1;
            #pragma unroll
            for (int d = 0; d < CPH; d++)
                bv += S_l[hd1 * 36 + cc1 * 6 + d] * vbase[(hd1 * 6 + d) * HW];
        }
        Bm1[jj] = (short)f2b(bv);
    }

    // mproj + epilogue
    #pragma unroll
    for (int t = 0; t < 3; t++) {
        short8 A0 = *(const short8*)(Wmp + (16 * t + m) * 64 + q * 8);
        short8 A1 = *(const short8*)(Wmp + (16 * t + m) * 64 + 32 + q * 8);
        f32x4 z = {0.f, 0.f, 0.f, 0.f};
        f32x4 D = __builtin_amdgcn_mfma_f32_16x16x32_bf16(A0, Bm0, z, 0, 0, 0);
        D = __builtin_amdgcn_mfma_f32_16x16x32_bf16(A1, Bm1, D, 0, 0, 0);
        #pragma unroll
        for (int g = 0; g < 4; g++) {
            int co = 16 * t + 4 * q + g;
            int idx = (b * Cc + co) * HW + hw;
            float xv = fl ? b2f(((const ushortT*)x)[idx]) : ((const float*)x)[idx];
            float res = xv + Dk[t][g] * caL[co] + D[g] * caL[48 + co];
            if (fl) ((ushortT*)out)[idx] = f2b(res);
            else    ((float*)out)[idx] = res;
        }
    }
}

// ---------------- host launch ----------------
extern "C" void kernel_launch(void* const* d_in, const int* in_sizes, int n_in,
                              void* d_out, int out_size, void* d_ws, size_t ws_size,
                              hipStream_t stream) {
    float* ws_f = (float*)d_ws;

    float* xn    = ws_f + FXN;
    float* bufA  = ws_f + FA;     // t1 -> Sp
    float* bufB  = ws_f + FB;     // t2
    float* bufC  = ws_f + FC;     // x1g -> qkv (spans C+D)
    float* bufD  = ws_f + FD;     // uf
    float* araw  = ws_f + FARAW;
    float* attn_t= ws_f + FATT;
    float* gap   = ws_f + FGAP;
    float* ca1   = ws_f + FCA1;
    float* ca2   = ws_f + FCA2;
    float* Smat  = ws_f + FS;
    float* wts   = ws_f + FW;
    ushortT* att_bf  = (ushortT*)(ws_f + FATTB);
    ushortT* Wt      = (ushortT*)(ws_f + FWT);
    ushortT* xnb     = (ushortT*)(ws_f + FXNB);
    ushortT* xmb     = (ushortT*)(ws_f + FXMB);
    ushortT* h_bf    = (ushortT*)(ws_f + FHBF);
    ushortT* Wpw     = (ushortT*)(ws_f + FWPW);
    ushortT* Wqk     = (ushortT*)(ws_f + FWQK);
    ushortT* Wkp     = (ushortT*)(ws_f + FWKP);
    ushortT* Wmp     = (ushortT*)(ws_f + FWMP);
    float* qkvr      = ws_f + FQKVR;

    float* qkv  = bufC;
    float* Sp   = bufA;
    const uint32_t* n1w_raw = (const uint32_t*)d_in[1];

    static const int wsizes[27] = {48,48,48,48,4608,864,4608,864,4608,432,24,384,32,
                                   1536,32,110592,3072,32,96,8,6912,1296,2304,2304,48,2304,48};
    static const int woffs[27] = {W_N1W,W_N1B,W_N2W,W_N2B,W_KDW1,W_KDW2,W_KC1A,W_KC1B,
                                  W_KPROJ,W_C2AW,W_C2AB,W_C2BW,W_C2BB,W_C211W,W_C211B,
                                  W_KW,W_KB,W_ATTG,W_GA1,W_TEMP,W_QKVW,W_QKVDW,W_MPROJ,
                                  W_CA1W,W_CA1B,W_CA2W,W_CA2B};
    ConvPack cp;
    for (int i = 0; i < 27; i++) {
        cp.src[i] = d_in[i + 1];
        cp.dstoff[i] = woffs[i];
        cp.n[i] = wsizes[i];
    }
    RawW rw;
    rw.kdw1 = d_in[5]; rw.kc1a = d_in[7]; rw.c211w = d_in[14]; rw.qkvw = d_in[21];
    rw.kproj = d_in[9]; rw.mproj = d_in[23]; rw.kw = d_in[16]; rw.kb = d_in[17];
    rw.n1w = d_in[1]; rw.n1b = d_in[2]; rw.n2w = d_in[3]; rw.n2b = d_in[4];

    k_prep<<<dim3(64, 34), 256, 0, stream>>>(cp, rw, wts, Wt, Wpw, Wqk, Wkp, Wmp,
                                             d_in[0], gap, xn, xnb, xmb, n1w_raw);
    k_pw1m<<<dim3(256), 256, 0, stream>>>(xnb, xmb, Wpw, Wqk, wts, bufA, bufB, attn_t, qkvr);
    k_dw<<<dim3(16, 216), 256, 0, stream>>>(bufA, bufB, xn, wts, bufC, bufD, araw);
    k_att<<<dim3(64), 256, 0, stream>>>(araw, attn_t, wts, att_bf);
    k_kba<<<dim3(64, 24), 256, 0, stream>>>(att_bf, bufD, bufC, Wt, wts, h_bf);
    k_qkvdw<<<dim3(16, 144), 256, 0, stream>>>(qkvr, wts, qkv);
    k_smat1<<<dim3(32, 4), 256, 0, stream>>>(qkv, Sp);
    k_smat2<<<dim3(32), 64, 0, stream>>>(Sp, gap, wts, Smat, ca1, ca2);
    k_finalm<<<dim3(256), 256, 0, stream>>>(d_in[0], n1w_raw, h_bf, Wkp, Wmp,
                                            qkv, Smat, ca1, ca2, d_out);
}

// Round 10
// 222.128 us; speedup vs baseline: 1.2169x; 1.0484x over previous
//
#include <hip/hip_runtime.h>
#include <hip/hip_bf16.h>
#include <cstdint>

typedef unsigned short ushortT;
typedef __attribute__((ext_vector_type(8))) short short8;
typedef __attribute__((ext_vector_type(4))) float f32x4;

// ---------------- problem constants ----------------
static constexpr int Bn = 4, Cc = 48, Hh = 64, Wd = 64, HW = 4096;
static constexpr int HID = 96, NSET = 32, INTERC = 24, HEADS = 8, CPH = 6;

// ---------------- ws layout (float offsets) ----------------
static constexpr int FXN   = 0;         // 786432  xn fp32 planar (c2a halo use)
static constexpr int FA    = 786432;    // 1572864 t1
static constexpr int FB    = 2359296;   // 1572864 t2
static constexpr int FC    = 3932160;   // 1572864 x1g -> qkv (spans C+D)
static constexpr int FD    = 5505024;   // 1572864 uf
static constexpr int FARAW = 7077888;   // 393216
static constexpr int FATT  = 7471104;   // 524288  attn_t fp32 [p][32]
static constexpr int FGAP  = 8781824;   // 192
static constexpr int FSP   = 8782400;   // 6144 Sp partials (32bh x 4chunk x 48)
static constexpr int FW    = 8790000;   // 147200 fp32 weights
static constexpr int FATTB = 8937200;   // 262144 fl: att_bf [p][32] bf16
static constexpr int FWT   = 9199344;   // 61440 fl: Wt bf16 (KBA)
static constexpr int FXNB  = 9260784;   // 524288 fl: xnb [p][64] bf16
static constexpr int FXMB  = 9785072;   // 524288 fl: xmb [p][64] bf16
static constexpr int FHBF  = 10309360;  // 786432 fl: h_bf [p][96] bf16
static constexpr int FWPW  = 11095792;  // 7168 fl: Wpw [224][64] bf16
static constexpr int FWQK  = 11102960;  // 4608 fl: Wqk [144][64] bf16
static constexpr int FWKP  = 11107568;  // 2304 fl: Wkp [48][96] bf16
static constexpr int FWMP  = 11109872;  // 1536 fl: Wmp [48][64] bf16
static constexpr int FQKVR = 11111424;  // 2359296 fl: qkvr planar
// total = 13470720 floats = 53.9 MB

// ---- weight offsets inside FW ----
static constexpr int W_N1W=0, W_N1B=48, W_N2W=96, W_N2B=144;
static constexpr int W_KDW1=192, W_KDW2=4800, W_KC1A=5664, W_KC1B=10272;
static constexpr int W_KPROJ=11136, W_C2AW=15744, W_C2AB=16176;
static constexpr int W_C2BW=16200, W_C2BB=16584, W_C211W=16616, W_C211B=18152;
static constexpr int W_KW=18184, W_KB=128776, W_ATTG=131848, W_GA1=131880;
static constexpr int W_TEMP=131976, W_QKVW=131984, W_QKVDW=138896, W_MPROJ=140192;
static constexpr int W_CA1W=142496, W_CA1B=144800, W_CA2W=144848, W_CA2B=147152;

__device__ __forceinline__ float b2f(ushortT u) {
    union { uint32_t i; float f; } v; v.i = ((uint32_t)u) << 16; return v.f;
}
__device__ __forceinline__ ushortT f2b(float f) {
    union { float f; uint32_t i; } v; v.f = f;
    uint32_t i = v.i;
    uint32_t lsb = (i >> 16) & 1u;
    i += 0x7fffu + lsb;
    return (ushortT)(i >> 16);
}
__device__ __forceinline__ int dtype_bf16(const uint32_t* n1w_raw) {
    return n1w_raw[0] == 0x3F803F80u;
}
__device__ __forceinline__ ushortT raw_bf(const void* p, int idx, int fl) {
    return fl ? ((const ushortT*)p)[idx] : f2b(((const float*)p)[idx]);
}
__device__ __forceinline__ float raw_f(const void* p, int idx, int fl) {
    return fl ? b2f(((const ushortT*)p)[idx]) : ((const float*)p)[idx];
}

// ---------------- prep: convert + all bf16 weight matrices + gap + LN ----------------
struct ConvPack {
    const void* src[27];
    int dstoff[27];
    int n[27];
};
struct RawW {
    const void* kdw1; const void* kc1a; const void* c211w; const void* qkvw;
    const void* kproj; const void* mproj; const void* kw; const void* kb;
    const void* n1w; const void* n1b; const void* n2w; const void* n2b;
};

__global__ void k_prep(ConvPack p, RawW rw, float* __restrict__ dst,
                       ushortT* __restrict__ Wt, ushortT* __restrict__ Wpw,
                       ushortT* __restrict__ Wqk, ushortT* __restrict__ Wkp,
                       ushortT* __restrict__ Wmp,
                       const void* __restrict__ x, float* __restrict__ gap,
                       float* __restrict__ xn, ushortT* __restrict__ xnb,
                       ushortT* __restrict__ xmb,
                       const uint32_t* __restrict__ n1w_raw) {
    int fl = dtype_bf16(n1w_raw);
    int y = blockIdx.y;
    if (y < 27) {
        int n = p.n[y];
        for (int i = blockIdx.x * 256 + threadIdx.x; i < n; i += 64 * 256) {
            dst[p.dstoff[y] + i] = raw_f(p.src[y], i, fl);
        }
    } else if (y == 27) {
        for (int u = blockIdx.x * 256 + threadIdx.x; u < 24 * 160 * 32; u += 64 * 256) {
            int n = u & 31;
            int rest = u >> 5;
            int r = rest % 160;
            int gr = rest / 160;
            ushortT out;
            if (r < 144) {
                int j = r >> 2, i = r & 3;
                out = raw_bf(rw.kw, n * 3456 + gr * 144 + i * 36 + j, fl);
            } else if (r < 148) {
                out = raw_bf(rw.kb, n * HID + gr * 4 + (r - 144), fl);
            } else out = 0;
            Wt[u] = out;
        }
    } else if (y == 28) {
        for (int u = blockIdx.x * 256 + threadIdx.x; u < 224 * 64; u += 64 * 256) {
            int co = u >> 6, c = u & 63;
            ushortT v = 0;
            if (c < 48) {
                if (co < 96)       v = raw_bf(rw.kdw1,  co * 48 + c, fl);
                else if (co < 192) v = raw_bf(rw.kc1a,  (co - 96) * 48 + c, fl);
                else               v = raw_bf(rw.c211w, (co - 192) * 48 + c, fl);
            }
            Wpw[u] = v;
        }
    } else if (y == 29) {
        for (int u = blockIdx.x * 256 + threadIdx.x; u < 144 * 64; u += 64 * 256) {
            int co = u >> 6, c = u & 63;
            Wqk[u] = (c < 48) ? raw_bf(rw.qkvw, co * 48 + c, fl) : (ushortT)0;
        }
    } else if (y == 30) {
        for (int u = blockIdx.x * 256 + threadIdx.x; u < 48 * 96; u += 64 * 256) {
            int co = u / 96, c = u % 96;
            Wkp[u] = raw_bf(rw.kproj, co * 96 + c, fl);
        }
    } else if (y == 31) {
        for (int u = blockIdx.x * 256 + threadIdx.x; u < 48 * 64; u += 64 * 256) {
            int co = u >> 6, c = u & 63;
            Wmp[u] = (c < 48) ? raw_bf(rw.mproj, co * 48 + c, fl) : (ushortT)0;
        }
    } else if (y == 32) {
        __shared__ float red[4];
        for (int bc = blockIdx.x; bc < Bn * Cc; bc += 64) {
            float s = 0.f;
            if (fl) {
                const ushortT* xb = (const ushortT*)x + bc * HW;
                for (int i = threadIdx.x; i < HW; i += 256) s += b2f(xb[i]);
            } else {
                const float* xb = (const float*)x + bc * HW;
                for (int i = threadIdx.x; i < HW; i += 256) s += xb[i];
            }
            #pragma unroll
            for (int o = 32; o > 0; o >>= 1) s += __shfl_down(s, o);
            int lane = threadIdx.x & 63, wv = threadIdx.x >> 6;
            if (lane == 0) red[wv] = s;
            __syncthreads();
            if (threadIdx.x == 0)
                gap[bc] = (red[0] + red[1] + red[2] + red[3]) * (1.f / HW);
            __syncthreads();
        }
    } else {
        // LN1 + LN2 from raw weights
        int pp = blockIdx.x * 256 + threadIdx.x;
        int b = pp >> 12, hw = pp & 4095;
        float xr[Cc];
        if (fl) {
            const ushortT* xb = (const ushortT*)x + b * Cc * HW + hw;
            #pragma unroll
            for (int c = 0; c < Cc; c++) xr[c] = b2f(xb[c * HW]);
        } else {
            const float* xb = (const float*)x + b * Cc * HW + hw;
            #pragma unroll
            for (int c = 0; c < Cc; c++) xr[c] = xb[c * HW];
        }
        float s = 0.f, ss = 0.f;
        #pragma unroll
        for (int c = 0; c < Cc; c++) { s += xr[c]; ss += xr[c] * xr[c]; }
        float mu = s * (1.f / Cc);
        float var = ss * (1.f / Cc) - mu * mu;
        float r = rsqrtf(var + 1e-6f);
        uint32_t pn[32], pm[32];
        #pragma unroll
        for (int i = 0; i < 24; i++) {
            float y0 = (xr[2 * i] - mu) * r, y1 = (xr[2 * i + 1] - mu) * r;
            float n0 = raw_f(rw.n1w, 2 * i, fl) * y0 + raw_f(rw.n1b, 2 * i, fl);
            float n1 = raw_f(rw.n1w, 2 * i + 1, fl) * y1 + raw_f(rw.n1b, 2 * i + 1, fl);
            float m0 = raw_f(rw.n2w, 2 * i, fl) * y0 + raw_f(rw.n2b, 2 * i, fl);
            float m1 = raw_f(rw.n2w, 2 * i + 1, fl) * y1 + raw_f(rw.n2b, 2 * i + 1, fl);
            xn[(b * Cc + 2 * i) * HW + hw] = n0;
            xn[(b * Cc + 2 * i + 1) * HW + hw] = n1;
            pn[i] = (uint32_t)f2b(n0) | ((uint32_t)f2b(n1) << 16);
            pm[i] = (uint32_t)f2b(m0) | ((uint32_t)f2b(m1) << 16);
        }
        #pragma unroll
        for (int i = 24; i < 32; i++) { pn[i] = 0; pm[i] = 0; }
        uint4* dn = (uint4*)(xnb + (size_t)pp * 64);
        uint4* dm = (uint4*)(xmb + (size_t)pp * 64);
        #pragma unroll
        for (int qd = 0; qd < 8; qd++) {
            uint4 v; v.x = pn[qd*4]; v.y = pn[qd*4+1]; v.z = pn[qd*4+2]; v.w = pn[qd*4+3];
            dn[qd] = v;
            uint4 u; u.x = pm[qd*4]; u.y = pm[qd*4+1]; u.z = pm[qd*4+2]; u.w = pm[qd*4+3];
            dm[qd] = u;
        }
    }
}

// ---------------- pw1m: [224x48]@xnb -> t1,t2,attn_t  AND  [144x48]@xmb -> qkvr. grid 256 x 256 ----------------
__global__ void __launch_bounds__(256) k_pw1m(const ushortT* __restrict__ xnb, const ushortT* __restrict__ xmb,
                       const ushortT* __restrict__ Wpw, const ushortT* __restrict__ Wqk,
                       const float* __restrict__ wts, float* __restrict__ t1,
                       float* __restrict__ t2, float* __restrict__ attn_t,
                       float* __restrict__ qkvr) {
    int wave = threadIdx.x >> 6, lane = threadIdx.x & 63;
    int m = lane & 15, q = lane >> 4;
    int p = blockIdx.x * 64 + wave * 16 + m;
    int b = p >> 12, hw = p & 4095;
    short8 B0 = *(const short8*)(xnb + (size_t)p * 64 + q * 8);
    short8 B1 = *(const short8*)(xnb + (size_t)p * 64 + 32 + q * 8);
    #pragma unroll
    for (int t = 0; t < 14; t++) {
        short8 A0 = *(const short8*)(Wpw + (16 * t + m) * 64 + q * 8);
        short8 A1 = *(const short8*)(Wpw + (16 * t + m) * 64 + 32 + q * 8);
        f32x4 z = {0.f, 0.f, 0.f, 0.f};
        f32x4 D = __builtin_amdgcn_mfma_f32_16x16x32_bf16(A0, B0, z, 0, 0, 0);
        D = __builtin_amdgcn_mfma_f32_16x16x32_bf16(A1, B1, D, 0, 0, 0);
        #pragma unroll
        for (int g = 0; g < 4; g++) {
            int co = 16 * t + 4 * q + g;
            if (t < 6) t1[(b * HID + co) * HW + hw] = D[g];
            else if (t < 12) t2[(b * HID + (co - 96)) * HW + hw] = D[g];
            else {
                int n = co - 192;
                attn_t[(size_t)p * 32 + n] = D[g] + wts[W_C211B + n];
            }
        }
    }
    short8 C0 = *(const short8*)(xmb + (size_t)p * 64 + q * 8);
    short8 C1 = *(const short8*)(xmb + (size_t)p * 64 + 32 + q * 8);
    #pragma unroll
    for (int t = 0; t < 9; t++) {
        short8 A0 = *(const short8*)(Wqk + (16 * t + m) * 64 + q * 8);
        short8 A1 = *(const short8*)(Wqk + (16 * t + m) * 64 + 32 + q * 8);
        f32x4 z = {0.f, 0.f, 0.f, 0.f};
        f32x4 D = __builtin_amdgcn_mfma_f32_16x16x32_bf16(A0, C0, z, 0, 0, 0);
        D = __builtin_amdgcn_mfma_f32_16x16x32_bf16(A1, C1, D, 0, 0, 0);
        #pragma unroll
        for (int g = 0; g < 4; g++) {
            int co = 16 * t + 4 * q + g;
            qkvr[(b * 144 + co) * HW + hw] = D[g];
        }
    }
}

// ---------------- depthwise/grouped 3x3: 4 px/thread, float4 IO. grid (16, 216) ----------------
__global__ void __launch_bounds__(256) k_dw(const float* __restrict__ t1, const float* __restrict__ t2,
                     const float* __restrict__ xn, const float* __restrict__ wts,
                     float* __restrict__ x1g, float* __restrict__ uf, float* __restrict__ araw) {
    int y = blockIdx.y;
    int pbase = blockIdx.x * 1024 + threadIdx.x * 4;
    int b = pbase >> 12, hw = pbase & 4095, h = hw >> 6, w0 = hw & 63;

    if (y < 192) {
        int c = (y < 96) ? y : y - 96;
        const float* base = (y < 96) ? t1 : t2;
        const float* wk = wts + ((y < 96) ? W_KDW2 : W_KC1B) + c * 9;
        const float* plane = base + (b * HID + c) * HW;

        float a0 = 0.f, a1 = 0.f, a2 = 0.f, a3 = 0.f;
        #pragma unroll
        for (int ki = 0; ki < 3; ki++) {
            int hh = h + ki - 1;
            if ((unsigned)hh < 64u) {
                const float* row = plane + hh * 64 + w0;
                float4 mm = *(const float4*)row;
                float lf = (w0 > 0) ? row[-1] : 0.f;
                float rt = (w0 < 60) ? row[4] : 0.f;
                float k0 = wk[ki * 3], k1 = wk[ki * 3 + 1], k2 = wk[ki * 3 + 2];
                a0 += k0 * lf   + k1 * mm.x + k2 * mm.y;
                a1 += k0 * mm.x + k1 * mm.y + k2 * mm.z;
                a2 += k0 * mm.y + k1 * mm.z + k2 * mm.w;
                a3 += k0 * mm.z + k1 * mm.w + k2 * rt;
            }
        }
        int idx = (b * HID + c) * HW + hw;
        if (y < 96) {
            float4 g;
            g.x = 0.5f * a0 * (1.f + erff(a0 * 0.70710678118654752f));
            g.y = 0.5f * a1 * (1.f + erff(a1 * 0.70710678118654752f));
            g.z = 0.5f * a2 * (1.f + erff(a2 * 0.70710678118654752f));
            g.w = 0.5f * a3 * (1.f + erff(a3 * 0.70710678118654752f));
            *(float4*)(x1g + idx) = g;
        } else {
            float4 o; o.x = a0; o.y = a1; o.z = a2; o.w = a3;
            *(float4*)(uf + idx) = o;
        }
    } else {
        int o = y - 192;
        float bias = wts[W_C2AB + o];
        float a0 = bias, a1 = bias, a2 = bias, a3 = bias;
        #pragma unroll
        for (int ic = 0; ic < 2; ic++) {
            const float* plane = xn + (b * Cc + 2 * o + ic) * HW;
            const float* wk = wts + W_C2AW + (o * 2 + ic) * 9;
            #pragma unroll
            for (int ki = 0; ki < 3; ki++) {
                int hh = h + ki - 1;
                if ((unsigned)hh < 64u) {
                    const float* row = plane + hh * 64 + w0;
                    float4 mm = *(const float4*)row;
                    float lf = (w0 > 0) ? row[-1] : 0.f;
                    float rt = (w0 < 60) ? row[4] : 0.f;
                    float k0 = wk[ki * 3], k1 = wk[ki * 3 + 1], k2 = wk[ki * 3 + 2];
                    a0 += k0 * lf   + k1 * mm.x + k2 * mm.y;
                    a1 += k0 * mm.x + k1 * mm.y + k2 * mm.z;
                    a2 += k0 * mm.y + k1 * mm.z + k2 * mm.w;
                    a3 += k0 * mm.z + k1 * mm.w + k2 * rt;
                }
            }
        }
        float4 out; out.x = a0; out.y = a1; out.z = a2; out.w = a3;
        *(float4*)(araw + (b * INTERC + o) * HW + hw) = out;
    }
}

// ---------------- attq: y<144 qkv depthwise; y=144..147 att(SimpleGate+c2b)->bf16. grid (16, 148) ----------------
__global__ void __launch_bounds__(256) k_attq(const float* __restrict__ qkvr, const float* __restrict__ araw,
                      const float* __restrict__ attn_t, const float* __restrict__ wts,
                      float* __restrict__ qkv, ushortT* __restrict__ att_bf) {
    int y = blockIdx.y;
    if (y < 144) {
        int ch = y;
        const float* wk = wts + W_QKVDW + ch * 9;
        int pbase = blockIdx.x * 1024 + threadIdx.x * 4;
        int b = pbase >> 12, hw = pbase & 4095, h = hw >> 6, w0 = hw & 63;
        const float* plane = qkvr + (b * 144 + ch) * HW;

        float a0 = 0.f, a1 = 0.f, a2 = 0.f, a3 = 0.f;
        #pragma unroll
        for (int ki = 0; ki < 3; ki++) {
            int hh = h + ki - 1;
            if ((unsigned)hh < 64u) {
                const float* row = plane + hh * 64 + w0;
                float4 mm = *(const float4*)row;
                float lf = (w0 > 0) ? row[-1] : 0.f;
                float rt = (w0 < 60) ? row[4] : 0.f;
                float k0 = wk[ki * 3], k1 = wk[ki * 3 + 1], k2 = wk[ki * 3 + 2];
                a0 += k0 * lf   + k1 * mm.x + k2 * mm.y;
                a1 += k0 * mm.x + k1 * mm.y + k2 * mm.z;
                a2 += k0 * mm.y + k1 * mm.z + k2 * mm.w;
                a3 += k0 * mm.z + k1 * mm.w + k2 * rt;
            }
        }
        float4 o; o.x = a0; o.y = a1; o.z = a2; o.w = a3;
        *(float4*)(qkv + (b * 144 + ch) * HW + hw) = o;
    } else {
        int p = ((y - 144) * 16 + blockIdx.x) * 256 + threadIdx.x;
        int b = p >> 12, hw = p & 4095;
        const float* ab = araw + b * INTERC * HW + hw;
        float sg[12];
        #pragma unroll
        for (int i = 0; i < 12; i++) sg[i] = ab[i * HW] * ab[(12 + i) * HW];
        const float* ct = attn_t + (size_t)p * 32;
        uint32_t packed[16];
        #pragma unroll
        for (int nq = 0; nq < 16; nq++) {
            float v2[2];
            #pragma unroll
            for (int u = 0; u < 2; u++) {
                int n = nq * 2 + u;
                float a = wts[W_C2BB + n];
                #pragma unroll
                for (int c = 0; c < 12; c++) a += wts[W_C2BW + n * 12 + c] * sg[c];
                v2[u] = wts[W_ATTG + n] * a + ct[n];
            }
            packed[nq] = (uint32_t)f2b(v2[0]) | ((uint32_t)f2b(v2[1]) << 16);
        }
        uint4* dst = (uint4*)(att_bf + (size_t)p * 32);
        #pragma unroll
        for (int qd = 0; qd < 4; qd++) {
            uint4 v; v.x = packed[qd*4]; v.y = packed[qd*4+1]; v.z = packed[qd*4+2]; v.w = packed[qd*4+3];
            dst[qd] = v;
        }
    }
}

// ---------------- kbas: y<24 KBA-MFMA -> h_bf; y=24..25 smat1 partials. grid (64, 26) ----------------
__global__ void __launch_bounds__(256) k_kbas(const ushortT* __restrict__ att_bf, const float* __restrict__ uf,
                     const float* __restrict__ x1g, const ushortT* __restrict__ Wt,
                     const float* __restrict__ wts, ushortT* __restrict__ h_bf,
                     const float* __restrict__ qkv, float* __restrict__ Sp) {
    if (blockIdx.y < 24) {
        int wave = threadIdx.x >> 6, lane = threadIdx.x & 63;
        int m = lane & 15, q = lane >> 4;
        int gr = blockIdx.y;

        short8 A[10];
        const ushortT* wtg = Wt + gr * 160 * 32;
        #pragma unroll
        for (int t = 0; t < 10; t++)
            A[t] = *(const short8*)(wtg + (16 * t + m) * 32 + q * 8);

        for (int tile = 0; tile < 4; tile++) {
            int p = blockIdx.x * 256 + wave * 64 + tile * 16 + m;
            int b = p >> 12, hw = p & 4095, h = hw >> 6, w = hw & 63;

            short8 Bf = *(const short8*)(att_bf + (size_t)p * 32 + q * 8);

            f32x4 D[10];
            #pragma unroll
            for (int t = 0; t < 10; t++) {
                f32x4 z = {0.f, 0.f, 0.f, 0.f};
                D[t] = __builtin_amdgcn_mfma_f32_16x16x32_bf16(A[t], Bf, z, 0, 0, 0);
            }

            float s0 = 0.f, s1 = 0.f, s2 = 0.f, s3 = 0.f;
            #pragma unroll
            for (int t = 0; t < 9; t++) {
                int j = 4 * t + q;
                int ci = j / 9;
                int kk = j - 9 * ci;
                int ki = kk / 3, kj = kk - 3 * ki;
                int hh = h + ki - 1, ww = w + kj - 1;
                float tap = 0.f;
                if ((unsigned)hh < 64u && (unsigned)ww < 64u)
                    tap = uf[(b * HID + gr * 4 + ci) * HW + hh * 64 + ww];
                s0 += D[t][0] * tap;
                s1 += D[t][1] * tap;
                s2 += D[t][2] * tap;
                s3 += D[t][3] * tap;
            }
            s0 += D[9][0]; s1 += D[9][1]; s2 += D[9][2]; s3 += D[9][3];

            s0 += __shfl_xor(s0, 16); s0 += __shfl_xor(s0, 32);
            s1 += __shfl_xor(s1, 16); s1 += __shfl_xor(s1, 32);
            s2 += __shfl_xor(s2, 16); s2 += __shfl_xor(s2, 32);
            s3 += __shfl_xor(s3, 16); s3 += __shfl_xor(s3, 32);

            float sel = (q == 0) ? s0 : ((q == 1) ? s1 : ((q == 2) ? s2 : s3));
            int ch = gr * 4 + q;
            int idx = (b * HID + ch) * HW + hw;
            float x2 = sel * wts[W_GA1 + ch] + uf[idx];
            float hv = x1g[idx] * x2;
            h_bf[(size_t)p * 96 + ch] = f2b(hv);
        }
    } else {
        int sub = (blockIdx.y - 24) * 64 + blockIdx.x;   // 0..127
        int bh = sub & 31, chunk = sub >> 5;
        int b = bh / HEADS, hd = bh % HEADS;
        const float* qb = qkv + (b * 144 + hd * CPH) * HW;
        const float* kb = qkv + (b * 144 + 48 + hd * CPH) * HW;
        float acc[48];
        #pragma unroll
        for (int t = 0; t < 48; t++) acc[t] = 0.f;
        #pragma unroll
        for (int i = 0; i < 4; i++) {
            int px = chunk * 1024 + i * 256 + threadIdx.x;
            float qv[CPH], kv[CPH];
            #pragma unroll
            for (int c = 0; c < CPH; c++) { qv[c] = qb[c * HW + px]; kv[c] = kb[c * HW + px]; }
            #pragma unroll
            for (int c = 0; c < CPH; c++) {
                #pragma unroll
                for (int d = 0; d < CPH; d++) acc[c * CPH + d] += qv[c] * kv[d];
                acc[36 + c] += qv[c] * qv[c];
                acc[42 + c] += kv[c] * kv[c];
            }
        }
        __shared__ float red[48 * 4];
        int lane = threadIdx.x & 63, wv = threadIdx.x >> 6;
        #pragma unroll
        for (int t = 0; t < 48; t++) {
            float v = acc[t];
            #pragma unroll
            for (int o = 32; o > 0; o >>= 1) v += __shfl_down(v, o);
            if (lane == 0) red[t * 4 + wv] = v;
        }
        __syncthreads();
        if (threadIdx.x < 48)
            Sp[(bh * 4 + chunk) * 48 + threadIdx.x] =
                red[threadIdx.x * 4] + red[threadIdx.x * 4 + 1] +
                red[threadIdx.x * 4 + 2] + red[threadIdx.x * 4 + 3];
    }
}

// ---------------- finalm: softmax(Sp)+ca in-block; kproj-MFMA + S@v + mproj-MFMA + residual. grid 256 x 256 ----------------
__global__ void __launch_bounds__(256) k_finalm(const void* __restrict__ x, const uint32_t* __restrict__ n1w_raw,
                        const ushortT* __restrict__ h_bf, const ushortT* __restrict__ Wkp,
                        const ushortT* __restrict__ Wmp, const float* __restrict__ qkv,
                        const float* __restrict__ Sp, const float* __restrict__ gap,
                        const float* __restrict__ wts, void* __restrict__ out) {
    int fl = dtype_bf16(n1w_raw);
    int wave = threadIdx.x >> 6, lane = threadIdx.x & 63;
    int m = lane & 15, q = lane >> 4;
    int p = blockIdx.x * 64 + wave * 16 + m;
    int hw = p & 4095;
    int bblk = (blockIdx.x * 64) >> 12;   // all 64 pixels of this block share one batch

    __shared__ float sm[384];     // per-head q/k/S sums for batch bblk
    __shared__ float S_l[288];
    __shared__ float caL[96];
    for (int i = threadIdx.x; i < 384; i += 256) {
        int hd = i / 48, k = i % 48;
        int bh = bblk * HEADS + hd;
        sm[i] = Sp[(bh * 4 + 0) * 48 + k] + Sp[(bh * 4 + 1) * 48 + k]
              + Sp[(bh * 4 + 2) * 48 + k] + Sp[(bh * 4 + 3) * 48 + k];
    }
    __syncthreads();
    if (threadIdx.x < 48) {
        int hd = threadIdx.x / 6, c = threadIdx.x % 6;
        const float* base = sm + hd * 48;
        float rqv = 1.f / fmaxf(sqrtf(base[36 + c]), 1e-12f);
        float tmp = wts[W_TEMP + hd];
        float row[CPH];
        #pragma unroll
        for (int d = 0; d < CPH; d++) {
            float rkv = 1.f / fmaxf(sqrtf(base[42 + d]), 1e-12f);
            row[d] = base[c * CPH + d] * rqv * rkv * tmp;
        }
        float mx = row[0];
        #pragma unroll
        for (int d = 1; d < CPH; d++) mx = fmaxf(mx, row[d]);
        float sum = 0.f;
        #pragma unroll
        for (int d = 0; d < CPH; d++) { row[d] = expf(row[d] - mx); sum += row[d]; }
        float inv = 1.f / sum;
        #pragma unroll
        for (int d = 0; d < CPH; d++) S_l[hd * 36 + c * CPH + d] = row[d] * inv;
    }
    if (threadIdx.x >= 64 && threadIdx.x < 160) {
        int i = threadIdx.x - 64;
        int which = i / 48, co = i % 48;
        const float* g = gap + bblk * Cc;
        float sacc = wts[(which ? W_CA2B : W_CA1B) + co];
        #pragma unroll
        for (int c = 0; c < Cc; c++)
            sacc += wts[(which ? W_CA2W : W_CA1W) + co * Cc + c] * g[c];
        caL[i] = sacc;
    }
    __syncthreads();

    // kproj: Dk = Wkp @ h_bf[p]
    short8 H0 = *(const short8*)(h_bf + (size_t)p * 96 + q * 8);
    short8 H1 = *(const short8*)(h_bf + (size_t)p * 96 + 32 + q * 8);
    short8 H2 = *(const short8*)(h_bf + (size_t)p * 96 + 64 + q * 8);
    f32x4 Dk[3];
    #pragma unroll
    for (int t = 0; t < 3; t++) {
        short8 A0 = *(const short8*)(Wkp + (16 * t + m) * 96 + q * 8);
        short8 A1 = *(const short8*)(Wkp + (16 * t + m) * 96 + 32 + q * 8);
        short8 A2 = *(const short8*)(Wkp + (16 * t + m) * 96 + 64 + q * 8);
        f32x4 z = {0.f, 0.f, 0.f, 0.f};
        f32x4 D = __builtin_amdgcn_mfma_f32_16x16x32_bf16(A0, H0, z, 0, 0, 0);
        D = __builtin_amdgcn_mfma_f32_16x16x32_bf16(A1, H1, D, 0, 0, 0);
        Dk[t] = __builtin_amdgcn_mfma_f32_16x16x32_bf16(A2, H2, D, 0, 0, 0);
    }

    // mdta B-fragments via S@v for this pixel
    const float* vbase = qkv + (bblk * 144 + 96) * HW + hw;
    short8 Bm0, Bm1;
    #pragma unroll
    for (int jj = 0; jj < 8; jj++) {
        int c0 = q * 8 + jj;
        int hd0 = c0 / 6, cc0 = c0 - 6 * hd0;
        float a = 0.f;
        #pragma unroll
        for (int d = 0; d < CPH; d++)
            a += S_l[hd0 * 36 + cc0 * 6 + d] * vbase[(hd0 * 6 + d) * HW];
        Bm0[jj] = (short)f2b(a);
        int c1 = 32 + q * 8 + jj;
        float bv = 0.f;
        if (c1 < 48) {
            int hd1 = c1 / 6, cc1 = c1 - 6 * hd1;
            #pragma unroll
            for (int d = 0; d < CPH; d++)
                bv += S_l[hd1 * 36 + cc1 * 6 + d] * vbase[(hd1 * 6 + d) * HW];
        }
        Bm1[jj] = (short)f2b(bv);
    }

    // mproj + epilogue
    #pragma unroll
    for (int t = 0; t < 3; t++) {
        short8 A0 = *(const short8*)(Wmp + (16 * t + m) * 64 + q * 8);
        short8 A1 = *(const short8*)(Wmp + (16 * t + m) * 64 + 32 + q * 8);
        f32x4 z = {0.f, 0.f, 0.f, 0.f};
        f32x4 D = __builtin_amdgcn_mfma_f32_16x16x32_bf16(A0, Bm0, z, 0, 0, 0);
        D = __builtin_amdgcn_mfma_f32_16x16x32_bf16(A1, Bm1, D, 0, 0, 0);
        #pragma unroll
        for (int g = 0; g < 4; g++) {
            int co = 16 * t + 4 * q + g;
            int idx = (bblk * Cc + co) * HW + hw;
            float xv = fl ? b2f(((const ushortT*)x)[idx]) : ((const float*)x)[idx];
            float res = xv + Dk[t][g] * caL[co] + D[g] * caL[48 + co];
            if (fl) ((ushortT*)out)[idx] = f2b(res);
            else    ((float*)out)[idx] = res;
        }
    }
}

// ---------------- host launch ----------------
extern "C" void kernel_launch(void* const* d_in, const int* in_sizes, int n_in,
                              void* d_out, int out_size, void* d_ws, size_t ws_size,
                              hipStream_t stream) {
    float* ws_f = (float*)d_ws;

    float* xn    = ws_f + FXN;
    float* bufA  = ws_f + FA;     // t1
    float* bufB  = ws_f + FB;     // t2
    float* bufC  = ws_f + FC;     // x1g -> qkv (spans C+D)
    float* bufD  = ws_f + FD;     // uf
    float* araw  = ws_f + FARAW;
    float* attn_t= ws_f + FATT;
    float* gap   = ws_f + FGAP;
    float* Sp    = ws_f + FSP;
    float* wts   = ws_f + FW;
    ushortT* att_bf  = (ushortT*)(ws_f + FATTB);
    ushortT* Wt      = (ushortT*)(ws_f + FWT);
    ushortT* xnb     = (ushortT*)(ws_f + FXNB);
    ushortT* xmb     = (ushortT*)(ws_f + FXMB);
    ushortT* h_bf    = (ushortT*)(ws_f + FHBF);
    ushortT* Wpw     = (ushortT*)(ws_f + FWPW);
    ushortT* Wqk     = (ushortT*)(ws_f + FWQK);
    ushortT* Wkp     = (ushortT*)(ws_f + FWKP);
    ushortT* Wmp     = (ushortT*)(ws_f + FWMP);
    float* qkvr      = ws_f + FQKVR;

    float* qkv  = bufC;
    const uint32_t* n1w_raw = (const uint32_t*)d_in[1];

    static const int wsizes[27] = {48,48,48,48,4608,864,4608,864,4608,432,24,384,32,
                                   1536,32,110592,3072,32,96,8,6912,1296,2304,2304,48,2304,48};
    static const int woffs[27] = {W_N1W,W_N1B,W_N2W,W_N2B,W_KDW1,W_KDW2,W_KC1A,W_KC1B,
                                  W_KPROJ,W_C2AW,W_C2AB,W_C2BW,W_C2BB,W_C211W,W_C211B,
                                  W_KW,W_KB,W_ATTG,W_GA1,W_TEMP,W_QKVW,W_QKVDW,W_MPROJ,
                                  W_CA1W,W_CA1B,W_CA2W,W_CA2B};
    ConvPack cp;
    for (int i = 0; i < 27; i++) {
        cp.src[i] = d_in[i + 1];
        cp.dstoff[i] = woffs[i];
        cp.n[i] = wsizes[i];
    }
    RawW rw;
    rw.kdw1 = d_in[5]; rw.kc1a = d_in[7]; rw.c211w = d_in[14]; rw.qkvw = d_in[21];
    rw.kproj = d_in[9]; rw.mproj = d_in[23]; rw.kw = d_in[16]; rw.kb = d_in[17];
    rw.n1w = d_in[1]; rw.n1b = d_in[2]; rw.n2w = d_in[3]; rw.n2b = d_in[4];

    k_prep<<<dim3(64, 34), 256, 0, stream>>>(cp, rw, wts, Wt, Wpw, Wqk, Wkp, Wmp,
                                             d_in[0], gap, xn, xnb, xmb, n1w_raw);
    k_pw1m<<<dim3(256), 256, 0, stream>>>(xnb, xmb, Wpw, Wqk, wts, bufA, bufB, attn_t, qkvr);
    k_dw<<<dim3(16, 216), 256, 0, stream>>>(bufA, bufB, xn, wts, bufC, bufD, araw);
    k_attq<<<dim3(16, 148), 256, 0, stream>>>(qkvr, araw, attn_t, wts, qkv, att_bf);
    k_kbas<<<dim3(64, 26), 256, 0, stream>>>(att_bf, bufD, bufC, Wt, wts, h_bf, qkv, Sp);
    k_finalm<<<dim3(256), 256, 0, stream>>>(d_in[0], n1w_raw, h_bf, Wkp, Wmp,
                                            qkv, Sp, gap, wts, d_out);
}

// Round 11
// 221.917 us; speedup vs baseline: 1.2181x; 1.0009x over previous
//
#include <hip/hip_runtime.h>
#include <hip/hip_bf16.h>
#include <cstdint>

typedef unsigned short ushortT;
typedef __attribute__((ext_vector_type(8))) short short8;
typedef __attribute__((ext_vector_type(4))) float f32x4;

// ---------------- problem constants ----------------
static constexpr int Bn = 4, Cc = 48, Hh = 64, Wd = 64, HW = 4096;
static constexpr int HID = 96, NSET = 32, INTERC = 24, HEADS = 8, CPH = 6;

// ---------------- ws layout (float offsets) ----------------
static constexpr int FXN   = 0;         // 786432  xn fp32 planar (c2a halo use)
static constexpr int FA    = 786432;    // 1572864 t1
static constexpr int FB    = 2359296;   // 1572864 t2
static constexpr int FC    = 3932160;   // 1572864 x1g
static constexpr int FD    = 5505024;   // 1572864 uf
static constexpr int FARAW = 7077888;   // 393216
static constexpr int FATT  = 7471104;   // 524288  attn_t fp32 [p][32]
static constexpr int FGAP  = 8781824;   // 192
static constexpr int FSP   = 8782400;   // 6144 Sp partials (32bh x 4chunk x 48)
static constexpr int FW    = 8790000;   // 147200 fp32 weights
static constexpr int FATTB = 8937200;   // 262144 fl: att_bf [p][32] bf16
static constexpr int FWT   = 9199344;   // 61440 fl: Wt bf16 (KBA)
static constexpr int FXNB  = 9260784;   // 524288 fl: xnb [p][64] bf16
static constexpr int FXMB  = 9785072;   // 524288 fl: xmb [p][64] bf16
static constexpr int FHBF  = 10309360;  // 786432 fl: h_bf [p][96] bf16
static constexpr int FWPW  = 11095792;  // 7168 fl: Wpw [224][64] bf16
static constexpr int FWQK  = 11102960;  // 4608 fl: Wqk [144][64] bf16
static constexpr int FWKP  = 11107568;  // 2304 fl: Wkp [48][96] bf16
static constexpr int FWMP  = 11109872;  // 1536 fl: Wmp [48][64] bf16
static constexpr int FQKVR = 11111424;  // 2359296 fl: qkvr planar
static constexpr int FQKV  = 13470720;  // 2359296 fl: qkv planar (DEDICATED - no aliasing)
// total = 15830016 floats = 63.3 MB

// ---- weight offsets inside FW ----
static constexpr int W_N1W=0, W_N1B=48, W_N2W=96, W_N2B=144;
static constexpr int W_KDW1=192, W_KDW2=4800, W_KC1A=5664, W_KC1B=10272;
static constexpr int W_KPROJ=11136, W_C2AW=15744, W_C2AB=16176;
static constexpr int W_C2BW=16200, W_C2BB=16584, W_C211W=16616, W_C211B=18152;
static constexpr int W_KW=18184, W_KB=128776, W_ATTG=131848, W_GA1=131880;
static constexpr int W_TEMP=131976, W_QKVW=131984, W_QKVDW=138896, W_MPROJ=140192;
static constexpr int W_CA1W=142496, W_CA1B=144800, W_CA2W=144848, W_CA2B=147152;

__device__ __forceinline__ float b2f(ushortT u) {
    union { uint32_t i; float f; } v; v.i = ((uint32_t)u) << 16; return v.f;
}
__device__ __forceinline__ ushortT f2b(float f) {
    union { float f; uint32_t i; } v; v.f = f;
    uint32_t i = v.i;
    uint32_t lsb = (i >> 16) & 1u;
    i += 0x7fffu + lsb;
    return (ushortT)(i >> 16);
}
__device__ __forceinline__ int dtype_bf16(const uint32_t* n1w_raw) {
    return n1w_raw[0] == 0x3F803F80u;
}
__device__ __forceinline__ ushortT raw_bf(const void* p, int idx, int fl) {
    return fl ? ((const ushortT*)p)[idx] : f2b(((const float*)p)[idx]);
}
__device__ __forceinline__ float raw_f(const void* p, int idx, int fl) {
    return fl ? b2f(((const ushortT*)p)[idx]) : ((const float*)p)[idx];
}

// ---------------- prep: convert + all bf16 weight matrices + gap + LN ----------------
struct ConvPack {
    const void* src[27];
    int dstoff[27];
    int n[27];
};
struct RawW {
    const void* kdw1; const void* kc1a; const void* c211w; const void* qkvw;
    const void* kproj; const void* mproj; const void* kw; const void* kb;
    const void* n1w; const void* n1b; const void* n2w; const void* n2b;
};

__global__ void k_prep(ConvPack p, RawW rw, float* __restrict__ dst,
                       ushortT* __restrict__ Wt, ushortT* __restrict__ Wpw,
                       ushortT* __restrict__ Wqk, ushortT* __restrict__ Wkp,
                       ushortT* __restrict__ Wmp,
                       const void* __restrict__ x, float* __restrict__ gap,
                       float* __restrict__ xn, ushortT* __restrict__ xnb,
                       ushortT* __restrict__ xmb,
                       const uint32_t* __restrict__ n1w_raw) {
    int fl = dtype_bf16(n1w_raw);
    int y = blockIdx.y;
    if (y < 27) {
        int n = p.n[y];
        for (int i = blockIdx.x * 256 + threadIdx.x; i < n; i += 64 * 256) {
            dst[p.dstoff[y] + i] = raw_f(p.src[y], i, fl);
        }
    } else if (y == 27) {
        for (int u = blockIdx.x * 256 + threadIdx.x; u < 24 * 160 * 32; u += 64 * 256) {
            int n = u & 31;
            int rest = u >> 5;
            int r = rest % 160;
            int gr = rest / 160;
            ushortT out;
            if (r < 144) {
                int j = r >> 2, i = r & 3;
                out = raw_bf(rw.kw, n * 3456 + gr * 144 + i * 36 + j, fl);
            } else if (r < 148) {
                out = raw_bf(rw.kb, n * HID + gr * 4 + (r - 144), fl);
            } else out = 0;
            Wt[u] = out;
        }
    } else if (y == 28) {
        for (int u = blockIdx.x * 256 + threadIdx.x; u < 224 * 64; u += 64 * 256) {
            int co = u >> 6, c = u & 63;
            ushortT v = 0;
            if (c < 48) {
                if (co < 96)       v = raw_bf(rw.kdw1,  co * 48 + c, fl);
                else if (co < 192) v = raw_bf(rw.kc1a,  (co - 96) * 48 + c, fl);
                else               v = raw_bf(rw.c211w, (co - 192) * 48 + c, fl);
            }
            Wpw[u] = v;
        }
    } else if (y == 29) {
        for (int u = blockIdx.x * 256 + threadIdx.x; u < 144 * 64; u += 64 * 256) {
            int co = u >> 6, c = u & 63;
            Wqk[u] = (c < 48) ? raw_bf(rw.qkvw, co * 48 + c, fl) : (ushortT)0;
        }
    } else if (y == 30) {
        for (int u = blockIdx.x * 256 + threadIdx.x; u < 48 * 96; u += 64 * 256) {
            int co = u / 96, c = u % 96;
            Wkp[u] = raw_bf(rw.kproj, co * 96 + c, fl);
        }
    } else if (y == 31) {
        for (int u = blockIdx.x * 256 + threadIdx.x; u < 48 * 64; u += 64 * 256) {
            int co = u >> 6, c = u & 63;
            Wmp[u] = (c < 48) ? raw_bf(rw.mproj, co * 48 + c, fl) : (ushortT)0;
        }
    } else if (y == 32) {
        __shared__ float red[4];
        for (int bc = blockIdx.x; bc < Bn * Cc; bc += 64) {
            float s = 0.f;
            if (fl) {
                const ushortT* xb = (const ushortT*)x + bc * HW;
                for (int i = threadIdx.x; i < HW; i += 256) s += b2f(xb[i]);
            } else {
                const float* xb = (const float*)x + bc * HW;
                for (int i = threadIdx.x; i < HW; i += 256) s += xb[i];
            }
            #pragma unroll
            for (int o = 32; o > 0; o >>= 1) s += __shfl_down(s, o);
            int lane = threadIdx.x & 63, wv = threadIdx.x >> 6;
            if (lane == 0) red[wv] = s;
            __syncthreads();
            if (threadIdx.x == 0)
                gap[bc] = (red[0] + red[1] + red[2] + red[3]) * (1.f / HW);
            __syncthreads();
        }
    } else {
        // LN1 + LN2 from raw weights
        int pp = blockIdx.x * 256 + threadIdx.x;
        int b = pp >> 12, hw = pp & 4095;
        float xr[Cc];
        if (fl) {
            const ushortT* xb = (const ushortT*)x + b * Cc * HW + hw;
            #pragma unroll
            for (int c = 0; c < Cc; c++) xr[c] = b2f(xb[c * HW]);
        } else {
            const float* xb = (const float*)x + b * Cc * HW + hw;
            #pragma unroll
            for (int c = 0; c < Cc; c++) xr[c] = xb[c * HW];
        }
        float s = 0.f, ss = 0.f;
        #pragma unroll
        for (int c = 0; c < Cc; c++) { s += xr[c]; ss += xr[c] * xr[c]; }
        float mu = s * (1.f / Cc);
        float var = ss * (1.f / Cc) - mu * mu;
        float r = rsqrtf(var + 1e-6f);
        uint32_t pn[32], pm[32];
        #pragma unroll
        for (int i = 0; i < 24; i++) {
            float y0 = (xr[2 * i] - mu) * r, y1 = (xr[2 * i + 1] - mu) * r;
            float n0 = raw_f(rw.n1w, 2 * i, fl) * y0 + raw_f(rw.n1b, 2 * i, fl);
            float n1 = raw_f(rw.n1w, 2 * i + 1, fl) * y1 + raw_f(rw.n1b, 2 * i + 1, fl);
            float m0 = raw_f(rw.n2w, 2 * i, fl) * y0 + raw_f(rw.n2b, 2 * i, fl);
            float m1 = raw_f(rw.n2w, 2 * i + 1, fl) * y1 + raw_f(rw.n2b, 2 * i + 1, fl);
            xn[(b * Cc + 2 * i) * HW + hw] = n0;
            xn[(b * Cc + 2 * i + 1) * HW + hw] = n1;
            pn[i] = (uint32_t)f2b(n0) | ((uint32_t)f2b(n1) << 16);
            pm[i] = (uint32_t)f2b(m0) | ((uint32_t)f2b(m1) << 16);
        }
        #pragma unroll
        for (int i = 24; i < 32; i++) { pn[i] = 0; pm[i] = 0; }
        uint4* dn = (uint4*)(xnb + (size_t)pp * 64);
        uint4* dm = (uint4*)(xmb + (size_t)pp * 64);
        #pragma unroll
        for (int qd = 0; qd < 8; qd++) {
            uint4 v; v.x = pn[qd*4]; v.y = pn[qd*4+1]; v.z = pn[qd*4+2]; v.w = pn[qd*4+3];
            dn[qd] = v;
            uint4 u; u.x = pm[qd*4]; u.y = pm[qd*4+1]; u.z = pm[qd*4+2]; u.w = pm[qd*4+3];
            dm[qd] = u;
        }
    }
}

// ---------------- pw1m: y=0 [224x48]@xnb -> t1,t2,attn_t ; y=1 [144x48]@xmb -> qkvr. grid (256,2) x 256 ----------------
__global__ void __launch_bounds__(256) k_pw1m(const ushortT* __restrict__ xnb, const ushortT* __restrict__ xmb,
                       const ushortT* __restrict__ Wpw, const ushortT* __restrict__ Wqk,
                       const float* __restrict__ wts, float* __restrict__ t1,
                       float* __restrict__ t2, float* __restrict__ attn_t,
                       float* __restrict__ qkvr) {
    int wave = threadIdx.x >> 6, lane = threadIdx.x & 63;
    int m = lane & 15, q = lane >> 4;
    int p = blockIdx.x * 64 + wave * 16 + m;
    int b = p >> 12, hw = p & 4095;
    if (blockIdx.y == 0) {
        short8 B0 = *(const short8*)(xnb + (size_t)p * 64 + q * 8);
        short8 B1 = *(const short8*)(xnb + (size_t)p * 64 + 32 + q * 8);
        #pragma unroll
        for (int t = 0; t < 14; t++) {
            short8 A0 = *(const short8*)(Wpw + (16 * t + m) * 64 + q * 8);
            short8 A1 = *(const short8*)(Wpw + (16 * t + m) * 64 + 32 + q * 8);
            f32x4 z = {0.f, 0.f, 0.f, 0.f};
            f32x4 D = __builtin_amdgcn_mfma_f32_16x16x32_bf16(A0, B0, z, 0, 0, 0);
            D = __builtin_amdgcn_mfma_f32_16x16x32_bf16(A1, B1, D, 0, 0, 0);
            #pragma unroll
            for (int g = 0; g < 4; g++) {
                int co = 16 * t + 4 * q + g;
                if (t < 6) t1[(b * HID + co) * HW + hw] = D[g];
                else if (t < 12) t2[(b * HID + (co - 96)) * HW + hw] = D[g];
                else {
                    int n = co - 192;
                    attn_t[(size_t)p * 32 + n] = D[g] + wts[W_C211B + n];
                }
            }
        }
    } else {
        short8 C0 = *(const short8*)(xmb + (size_t)p * 64 + q * 8);
        short8 C1 = *(const short8*)(xmb + (size_t)p * 64 + 32 + q * 8);
        #pragma unroll
        for (int t = 0; t < 9; t++) {
            short8 A0 = *(const short8*)(Wqk + (16 * t + m) * 64 + q * 8);
            short8 A1 = *(const short8*)(Wqk + (16 * t + m) * 64 + 32 + q * 8);
            f32x4 z = {0.f, 0.f, 0.f, 0.f};
            f32x4 D = __builtin_amdgcn_mfma_f32_16x16x32_bf16(A0, C0, z, 0, 0, 0);
            D = __builtin_amdgcn_mfma_f32_16x16x32_bf16(A1, C1, D, 0, 0, 0);
            #pragma unroll
            for (int g = 0; g < 4; g++) {
                int co = 16 * t + 4 * q + g;
                qkvr[(b * 144 + co) * HW + hw] = D[g];
            }
        }
    }
}

// ---------------- dw: y<96 kdw2->gelu->x1g ; y<192 kc1b->uf ; y<216 c2a->araw ; y<360 qkvdw->qkv. grid (16, 360) ----------------
__global__ void __launch_bounds__(256) k_dw(const float* __restrict__ t1, const float* __restrict__ t2,
                     const float* __restrict__ xn, const float* __restrict__ qkvr,
                     const float* __restrict__ wts,
                     float* __restrict__ x1g, float* __restrict__ uf,
                     float* __restrict__ araw, float* __restrict__ qkv) {
    int y = blockIdx.y;
    int pbase = blockIdx.x * 1024 + threadIdx.x * 4;
    int b = pbase >> 12, hw = pbase & 4095, h = hw >> 6, w0 = hw & 63;

    if (y < 192) {
        int c = (y < 96) ? y : y - 96;
        const float* base = (y < 96) ? t1 : t2;
        const float* wk = wts + ((y < 96) ? W_KDW2 : W_KC1B) + c * 9;
        const float* plane = base + (b * HID + c) * HW;

        float a0 = 0.f, a1 = 0.f, a2 = 0.f, a3 = 0.f;
        #pragma unroll
        for (int ki = 0; ki < 3; ki++) {
            int hh = h + ki - 1;
            if ((unsigned)hh < 64u) {
                const float* row = plane + hh * 64 + w0;
                float4 mm = *(const float4*)row;
                float lf = (w0 > 0) ? row[-1] : 0.f;
                float rt = (w0 < 60) ? row[4] : 0.f;
                float k0 = wk[ki * 3], k1 = wk[ki * 3 + 1], k2 = wk[ki * 3 + 2];
                a0 += k0 * lf   + k1 * mm.x + k2 * mm.y;
                a1 += k0 * mm.x + k1 * mm.y + k2 * mm.z;
                a2 += k0 * mm.y + k1 * mm.z + k2 * mm.w;
                a3 += k0 * mm.z + k1 * mm.w + k2 * rt;
            }
        }
        int idx = (b * HID + c) * HW + hw;
        if (y < 96) {
            float4 g;
            g.x = 0.5f * a0 * (1.f + erff(a0 * 0.70710678118654752f));
            g.y = 0.5f * a1 * (1.f + erff(a1 * 0.70710678118654752f));
            g.z = 0.5f * a2 * (1.f + erff(a2 * 0.70710678118654752f));
            g.w = 0.5f * a3 * (1.f + erff(a3 * 0.70710678118654752f));
            *(float4*)(x1g + idx) = g;
        } else {
            float4 o; o.x = a0; o.y = a1; o.z = a2; o.w = a3;
            *(float4*)(uf + idx) = o;
        }
    } else if (y < 216) {
        int o = y - 192;
        float bias = wts[W_C2AB + o];
        float a0 = bias, a1 = bias, a2 = bias, a3 = bias;
        #pragma unroll
        for (int ic = 0; ic < 2; ic++) {
            const float* plane = xn + (b * Cc + 2 * o + ic) * HW;
            const float* wk = wts + W_C2AW + (o * 2 + ic) * 9;
            #pragma unroll
            for (int ki = 0; ki < 3; ki++) {
                int hh = h + ki - 1;
                if ((unsigned)hh < 64u) {
                    const float* row = plane + hh * 64 + w0;
                    float4 mm = *(const float4*)row;
                    float lf = (w0 > 0) ? row[-1] : 0.f;
                    float rt = (w0 < 60) ? row[4] : 0.f;
                    float k0 = wk[ki * 3], k1 = wk[ki * 3 + 1], k2 = wk[ki * 3 + 2];
                    a0 += k0 * lf   + k1 * mm.x + k2 * mm.y;
                    a1 += k0 * mm.x + k1 * mm.y + k2 * mm.z;
                    a2 += k0 * mm.y + k1 * mm.z + k2 * mm.w;
                    a3 += k0 * mm.z + k1 * mm.w + k2 * rt;
                }
            }
        }
        float4 out; out.x = a0; out.y = a1; out.z = a2; out.w = a3;
        *(float4*)(araw + (b * INTERC + o) * HW + hw) = out;
    } else {
        int ch = y - 216;   // 0..143
        const float* wk = wts + W_QKVDW + ch * 9;
        const float* plane = qkvr + (b * 144 + ch) * HW;

        float a0 = 0.f, a1 = 0.f, a2 = 0.f, a3 = 0.f;
        #pragma unroll
        for (int ki = 0; ki < 3; ki++) {
            int hh = h + ki - 1;
            if ((unsigned)hh < 64u) {
                const float* row = plane + hh * 64 + w0;
                float4 mm = *(const float4*)row;
                float lf = (w0 > 0) ? row[-1] : 0.f;
                float rt = (w0 < 60) ? row[4] : 0.f;
                float k0 = wk[ki * 3], k1 = wk[ki * 3 + 1], k2 = wk[ki * 3 + 2];
                a0 += k0 * lf   + k1 * mm.x + k2 * mm.y;
                a1 += k0 * mm.x + k1 * mm.y + k2 * mm.z;
                a2 += k0 * mm.y + k1 * mm.z + k2 * mm.w;
                a3 += k0 * mm.z + k1 * mm.w + k2 * rt;
            }
        }
        float4 o; o.x = a0; o.y = a1; o.z = a2; o.w = a3;
        *(float4*)(qkv + (b * 144 + ch) * HW + hw) = o;
    }
}

// ---------------- attsm: x<64 att(SimpleGate+c2b)->att_bf ; x>=64 smat partials. grid (192) x 256 ----------------
__global__ void __launch_bounds__(256) k_attsm(const float* __restrict__ araw, const float* __restrict__ attn_t,
                       const float* __restrict__ qkv, const float* __restrict__ wts,
                       ushortT* __restrict__ att_bf, float* __restrict__ Sp) {
    if (blockIdx.x < 64) {
        int p = blockIdx.x * 256 + threadIdx.x;
        int b = p >> 12, hw = p & 4095;
        const float* ab = araw + b * INTERC * HW + hw;
        float sg[12];
        #pragma unroll
        for (int i = 0; i < 12; i++) sg[i] = ab[i * HW] * ab[(12 + i) * HW];
        const float* ct = attn_t + (size_t)p * 32;
        uint32_t packed[16];
        #pragma unroll
        for (int nq = 0; nq < 16; nq++) {
            float v2[2];
            #pragma unroll
            for (int u = 0; u < 2; u++) {
                int n = nq * 2 + u;
                float a = wts[W_C2BB + n];
                #pragma unroll
                for (int c = 0; c < 12; c++) a += wts[W_C2BW + n * 12 + c] * sg[c];
                v2[u] = wts[W_ATTG + n] * a + ct[n];
            }
            packed[nq] = (uint32_t)f2b(v2[0]) | ((uint32_t)f2b(v2[1]) << 16);
        }
        uint4* dst = (uint4*)(att_bf + (size_t)p * 32);
        #pragma unroll
        for (int qd = 0; qd < 4; qd++) {
            uint4 v; v.x = packed[qd*4]; v.y = packed[qd*4+1]; v.z = packed[qd*4+2]; v.w = packed[qd*4+3];
            dst[qd] = v;
        }
    } else {
        int sub = blockIdx.x - 64;          // 0..127
        int bh = sub & 31, chunk = sub >> 5;
        int b = bh / HEADS, hd = bh % HEADS;
        const float* qb = qkv + (b * 144 + hd * CPH) * HW;
        const float* kb = qkv + (b * 144 + 48 + hd * CPH) * HW;
        float acc[48];
        #pragma unroll
        for (int t = 0; t < 48; t++) acc[t] = 0.f;
        #pragma unroll
        for (int i = 0; i < 4; i++) {
            int px = chunk * 1024 + i * 256 + threadIdx.x;
            float qv[CPH], kv[CPH];
            #pragma unroll
            for (int c = 0; c < CPH; c++) { qv[c] = qb[c * HW + px]; kv[c] = kb[c * HW + px]; }
            #pragma unroll
            for (int c = 0; c < CPH; c++) {
                #pragma unroll
                for (int d = 0; d < CPH; d++) acc[c * CPH + d] += qv[c] * kv[d];
                acc[36 + c] += qv[c] * qv[c];
                acc[42 + c] += kv[c] * kv[c];
            }
        }
        __shared__ float red[48 * 4];
        int lane = threadIdx.x & 63, wv = threadIdx.x >> 6;
        #pragma unroll
        for (int t = 0; t < 48; t++) {
            float v = acc[t];
            #pragma unroll
            for (int o = 32; o > 0; o >>= 1) v += __shfl_down(v, o);
            if (lane == 0) red[t * 4 + wv] = v;
        }
        __syncthreads();
        if (threadIdx.x < 48)
            Sp[(bh * 4 + chunk) * 48 + threadIdx.x] =
                red[threadIdx.x * 4] + red[threadIdx.x * 4 + 1] +
                red[threadIdx.x * 4 + 2] + red[threadIdx.x * 4 + 3];
    }
}

// ---------------- KBA core via MFMA -> h_bf [p][96] bf16. grid (64,24) x 256 ----------------
__global__ void __launch_bounds__(256) k_kba(const ushortT* __restrict__ att_bf, const float* __restrict__ uf,
                     const float* __restrict__ x1g, const ushortT* __restrict__ Wt,
                     const float* __restrict__ wts, ushortT* __restrict__ h_bf) {
    int wave = threadIdx.x >> 6, lane = threadIdx.x & 63;
    int m = lane & 15, q = lane >> 4;
    int gr = blockIdx.y;

    short8 A[10];
    const ushortT* wtg = Wt + gr * 160 * 32;
    #pragma unroll
    for (int t = 0; t < 10; t++)
        A[t] = *(const short8*)(wtg + (16 * t + m) * 32 + q * 8);

    for (int tile = 0; tile < 4; tile++) {
        int p = blockIdx.x * 256 + wave * 64 + tile * 16 + m;
        int b = p >> 12, hw = p & 4095, h = hw >> 6, w = hw & 63;

        short8 Bf = *(const short8*)(att_bf + (size_t)p * 32 + q * 8);

        f32x4 D[10];
        #pragma unroll
        for (int t = 0; t < 10; t++) {
            f32x4 z = {0.f, 0.f, 0.f, 0.f};
            D[t] = __builtin_amdgcn_mfma_f32_16x16x32_bf16(A[t], Bf, z, 0, 0, 0);
        }

        float s0 = 0.f, s1 = 0.f, s2 = 0.f, s3 = 0.f;
        #pragma unroll
        for (int t = 0; t < 9; t++) {
            int j = 4 * t + q;
            int ci = j / 9;
            int kk = j - 9 * ci;
            int ki = kk / 3, kj = kk - 3 * ki;
            int hh = h + ki - 1, ww = w + kj - 1;
            float tap = 0.f;
            if ((unsigned)hh < 64u && (unsigned)ww < 64u)
                tap = uf[(b * HID + gr * 4 + ci) * HW + hh * 64 + ww];
            s0 += D[t][0] * tap;
            s1 += D[t][1] * tap;
            s2 += D[t][2] * tap;
            s3 += D[t][3] * tap;
        }
        s0 += D[9][0]; s1 += D[9][1]; s2 += D[9][2]; s3 += D[9][3];

        s0 += __shfl_xor(s0, 16); s0 += __shfl_xor(s0, 32);
        s1 += __shfl_xor(s1, 16); s1 += __shfl_xor(s1, 32);
        s2 += __shfl_xor(s2, 16); s2 += __shfl_xor(s2, 32);
        s3 += __shfl_xor(s3, 16); s3 += __shfl_xor(s3, 32);

        float sel = (q == 0) ? s0 : ((q == 1) ? s1 : ((q == 2) ? s2 : s3));
        int ch = gr * 4 + q;
        int idx = (b * HID + ch) * HW + hw;
        float x2 = sel * wts[W_GA1 + ch] + uf[idx];
        float hv = x1g[idx] * x2;
        h_bf[(size_t)p * 96 + ch] = f2b(hv);
    }
}

// ---------------- finalm: softmax(Sp)+ca in-block; kproj-MFMA + S@v + mproj-MFMA + residual. grid 256 x 256 ----------------
__global__ void __launch_bounds__(256) k_finalm(const void* __restrict__ x, const uint32_t* __restrict__ n1w_raw,
                        const ushortT* __restrict__ h_bf, const ushortT* __restrict__ Wkp,
                        const ushortT* __restrict__ Wmp, const float* __restrict__ qkv,
                        const float* __restrict__ Sp, const float* __restrict__ gap,
                        const float* __restrict__ wts, void* __restrict__ out) {
    int fl = dtype_bf16(n1w_raw);
    int wave = threadIdx.x >> 6, lane = threadIdx.x & 63;
    int m = lane & 15, q = lane >> 4;
    int p = blockIdx.x * 64 + wave * 16 + m;
    int hw = p & 4095;
    int bblk = (blockIdx.x * 64) >> 12;

    __shared__ float sm[384];
    __shared__ float S_l[288];
    __shared__ float caL[96];
    for (int i = threadIdx.x; i < 384; i += 256) {
        int hd = i / 48, k = i % 48;
        int bh = bblk * HEADS + hd;
        sm[i] = Sp[(bh * 4 + 0) * 48 + k] + Sp[(bh * 4 + 1) * 48 + k]
              + Sp[(bh * 4 + 2) * 48 + k] + Sp[(bh * 4 + 3) * 48 + k];
    }
    __syncthreads();
    if (threadIdx.x < 48) {
        int hd = threadIdx.x / 6, c = threadIdx.x % 6;
        const float* base = sm + hd * 48;
        float rqv = 1.f / fmaxf(sqrtf(base[36 + c]), 1e-12f);
        float tmp = wts[W_TEMP + hd];
        float row[CPH];
        #pragma unroll
        for (int d = 0; d < CPH; d++) {
            float rkv = 1.f / fmaxf(sqrtf(base[42 + d]), 1e-12f);
            row[d] = base[c * CPH + d] * rqv * rkv * tmp;
        }
        float mx = row[0];
        #pragma unroll
        for (int d = 1; d < CPH; d++) mx = fmaxf(mx, row[d]);
        float sum = 0.f;
        #pragma unroll
        for (int d = 0; d < CPH; d++) { row[d] = expf(row[d] - mx); sum += row[d]; }
        float inv = 1.f / sum;
        #pragma unroll
        for (int d = 0; d < CPH; d++) S_l[hd * 36 + c * CPH + d] = row[d] * inv;
    }
    if (threadIdx.x >= 64 && threadIdx.x < 160) {
        int i = threadIdx.x - 64;
        int which = i / 48, co = i % 48;
        const float* g = gap + bblk * Cc;
        float sacc = wts[(which ? W_CA2B : W_CA1B) + co];
        #pragma unroll
        for (int c = 0; c < Cc; c++)
            sacc += wts[(which ? W_CA2W : W_CA1W) + co * Cc + c] * g[c];
        caL[i] = sacc;
    }
    __syncthreads();

    // kproj: Dk = Wkp @ h_bf[p]
    short8 H0 = *(const short8*)(h_bf + (size_t)p * 96 + q * 8);
    short8 H1 = *(const short8*)(h_bf + (size_t)p * 96 + 32 + q * 8);
    short8 H2 = *(const short8*)(h_bf + (size_t)p * 96 + 64 + q * 8);
    f32x4 Dk[3];
    #pragma unroll
    for (int t = 0; t < 3; t++) {
        short8 A0 = *(const short8*)(Wkp + (16 * t + m) * 96 + q * 8);
        short8 A1 = *(const short8*)(Wkp + (16 * t + m) * 96 + 32 + q * 8);
        short8 A2 = *(const short8*)(Wkp + (16 * t + m) * 96 + 64 + q * 8);
        f32x4 z = {0.f, 0.f, 0.f, 0.f};
        f32x4 D = __builtin_amdgcn_mfma_f32_16x16x32_bf16(A0, H0, z, 0, 0, 0);
        D = __builtin_amdgcn_mfma_f32_16x16x32_bf16(A1, H1, D, 0, 0, 0);
        Dk[t] = __builtin_amdgcn_mfma_f32_16x16x32_bf16(A2, H2, D, 0, 0, 0);
    }

    // mdta B-fragments via S@v for this pixel
    const float* vbase = qkv + (bblk * 144 + 96) * HW + hw;
    short8 Bm0, Bm1;
    #pragma unroll
    for (int jj = 0; jj < 8; jj++) {
        int c0 = q * 8 + jj;
        int hd0 = c0 / 6, cc0 = c0 - 6 * hd0;
        float a = 0.f;
        #pragma unroll
        for (int d = 0; d < CPH; d++)
            a += S_l[hd0 * 36 + cc0 * 6 + d] * vbase[(hd0 * 6 + d) * HW];
        Bm0[jj] = (short)f2b(a);
        int c1 = 32 + q * 8 + jj;
        float bv = 0.f;
        if (c1 < 48) {
            int hd1 = c1 / 6, cc1 = c1 - 6 * hd1;
            #pragma unroll
            for (int d = 0; d < CPH; d++)
                bv += S_l[hd1 * 36 + cc1 * 6 + d] * vbase[(hd1 * 6 + d) * HW];
        }
        Bm1[jj] = (short)f2b(bv);
    }

    // mproj + epilogue
    #pragma unroll
    for (int t = 0; t < 3; t++) {
        short8 A0 = *(const short8*)(Wmp + (16 * t + m) * 64 + q * 8);
        short8 A1 = *(const short8*)(Wmp + (16 * t + m) * 64 + 32 + q * 8);
        f32x4 z = {0.f, 0.f, 0.f, 0.f};
        f32x4 D = __builtin_amdgcn_mfma_f32_16x16x32_bf16(A0, Bm0, z, 0, 0, 0);
        D = __builtin_amdgcn_mfma_f32_16x16x32_bf16(A1, Bm1, D, 0, 0, 0);
        #pragma unroll
        for (int g = 0; g < 4; g++) {
            int co = 16 * t + 4 * q + g;
            int idx = (bblk * Cc + co) * HW + hw;
            float xv = fl ? b2f(((const ushortT*)x)[idx]) : ((const float*)x)[idx];
            float res = xv + Dk[t][g] * caL[co] + D[g] * caL[48 + co];
            if (fl) ((ushortT*)out)[idx] = f2b(res);
            else    ((float*)out)[idx] = res;
        }
    }
}

// ---------------- host launch ----------------
extern "C" void kernel_launch(void* const* d_in, const int* in_sizes, int n_in,
                              void* d_out, int out_size, void* d_ws, size_t ws_size,
                              hipStream_t stream) {
    float* ws_f = (float*)d_ws;

    float* xn    = ws_f + FXN;
    float* bufA  = ws_f + FA;     // t1
    float* bufB  = ws_f + FB;     // t2
    float* x1g   = ws_f + FC;
    float* uf    = ws_f + FD;
    float* araw  = ws_f + FARAW;
    float* attn_t= ws_f + FATT;
    float* gap   = ws_f + FGAP;
    float* Sp    = ws_f + FSP;
    float* wts   = ws_f + FW;
    ushortT* att_bf  = (ushortT*)(ws_f + FATTB);
    ushortT* Wt      = (ushortT*)(ws_f + FWT);
    ushortT* xnb     = (ushortT*)(ws_f + FXNB);
    ushortT* xmb     = (ushortT*)(ws_f + FXMB);
    ushortT* h_bf    = (ushortT*)(ws_f + FHBF);
    ushortT* Wpw     = (ushortT*)(ws_f + FWPW);
    ushortT* Wqk     = (ushortT*)(ws_f + FWQK);
    ushortT* Wkp     = (ushortT*)(ws_f + FWKP);
    ushortT* Wmp     = (ushortT*)(ws_f + FWMP);
    float* qkvr      = ws_f + FQKVR;
    float* qkv       = ws_f + FQKV;   // dedicated - no aliasing with x1g/uf

    const uint32_t* n1w_raw = (const uint32_t*)d_in[1];

    static const int wsizes[27] = {48,48,48,48,4608,864,4608,864,4608,432,24,384,32,
                                   1536,32,110592,3072,32,96,8,6912,1296,2304,2304,48,2304,48};
    static const int woffs[27] = {W_N1W,W_N1B,W_N2W,W_N2B,W_KDW1,W_KDW2,W_KC1A,W_KC1B,
                                  W_KPROJ,W_C2AW,W_C2AB,W_C2BW,W_C2BB,W_C211W,W_C211B,
                                  W_KW,W_KB,W_ATTG,W_GA1,W_TEMP,W_QKVW,W_QKVDW,W_MPROJ,
                                  W_CA1W,W_CA1B,W_CA2W,W_CA2B};
    ConvPack cp;
    for (int i = 0; i < 27; i++) {
        cp.src[i] = d_in[i + 1];
        cp.dstoff[i] = woffs[i];
        cp.n[i] = wsizes[i];
    }
    RawW rw;
    rw.kdw1 = d_in[5]; rw.kc1a = d_in[7]; rw.c211w = d_in[14]; rw.qkvw = d_in[21];
    rw.kproj = d_in[9]; rw.mproj = d_in[23]; rw.kw = d_in[16]; rw.kb = d_in[17];
    rw.n1w = d_in[1]; rw.n1b = d_in[2]; rw.n2w = d_in[3]; rw.n2b = d_in[4];

    k_prep<<<dim3(64, 34), 256, 0, stream>>>(cp, rw, wts, Wt, Wpw, Wqk, Wkp, Wmp,
                                             d_in[0], gap, xn, xnb, xmb, n1w_raw);
    k_pw1m<<<dim3(256, 2), 256, 0, stream>>>(xnb, xmb, Wpw, Wqk, wts, bufA, bufB, attn_t, qkvr);
    k_dw<<<dim3(16, 360), 256, 0, stream>>>(bufA, bufB, xn, qkvr, wts, x1g, uf, araw, qkv);
    k_attsm<<<dim3(192), 256, 0, stream>>>(araw, attn_t, qkv, wts, att_bf, Sp);
    k_kba<<<dim3(64, 24), 256, 0, stream>>>(att_bf, uf, x1g, Wt, wts, h_bf);
    k_finalm<<<dim3(256), 256, 0, stream>>>(d_in[0], n1w_raw, h_bf, Wkp, Wmp,
                                            qkv, Sp, gap, wts, d_out);
}

// Round 12
// 202.761 us; speedup vs baseline: 1.3332x; 1.0945x over previous
//
#include <hip/hip_runtime.h>
#include <hip/hip_bf16.h>
#include <cstdint>

typedef unsigned short ushortT;
typedef __attribute__((ext_vector_type(8))) short short8;
typedef __attribute__((ext_vector_type(4))) float f32x4;

// ---------------- problem constants ----------------
static constexpr int Bn = 4, Cc = 48, Hh = 64, Wd = 64, HW = 4096;
static constexpr int HID = 96, NSET = 32, INTERC = 24, HEADS = 8, CPH = 6;

// ---------------- ws layout (float offsets) ----------------
static constexpr int FXN   = 0;         // 786432  xn fp32 planar (c2a halo use)
static constexpr int FA    = 786432;    // 1572864 t1
static constexpr int FB    = 2359296;   // 1572864 t2
static constexpr int FC    = 3932160;   // 1572864 x1g
static constexpr int FD    = 5505024;   // 1572864 uf
static constexpr int FARAW = 7077888;   // 393216
static constexpr int FATT  = 7471104;   // 524288  attn_t fp32 [p][32]
static constexpr int FGAP  = 8781824;   // 192
static constexpr int FSP   = 8782400;   // 6144 Sp partials (32bh x 4chunk x 48)
static constexpr int FW    = 8790000;   // 147200 fp32 weights
static constexpr int FATTB = 8937200;   // 262144 fl: att_bf [p][32] bf16
static constexpr int FWT   = 9199344;   // 61440 fl: Wt bf16 (KBA)
static constexpr int FXNB  = 9260784;   // 524288 fl: xnb [p][64] bf16
static constexpr int FXMB  = 9785072;   // 524288 fl: xmb [p][64] bf16
static constexpr int FHBF  = 10309360;  // 786432 fl: h_bf [p][96] bf16
static constexpr int FWPW  = 11095792;  // 7168 fl: Wpw [224][64] bf16
static constexpr int FWQK  = 11102960;  // 4608 fl: Wqk [144][64] bf16
static constexpr int FWKP  = 11107568;  // 2304 fl: Wkp [48][96] bf16
static constexpr int FWMP  = 11109872;  // 1536 fl: Wmp [48][64] bf16
static constexpr int FQKVR = 11111424;  // 2359296 fl: qkvr planar
static constexpr int FQKV  = 13470720;  // 2359296 fl: qkv planar (dedicated)
// total = 15830016 floats = 63.3 MB

// ---- weight offsets inside FW ----
static constexpr int W_N1W=0, W_N1B=48, W_N2W=96, W_N2B=144;
static constexpr int W_KDW1=192, W_KDW2=4800, W_KC1A=5664, W_KC1B=10272;
static constexpr int W_KPROJ=11136, W_C2AW=15744, W_C2AB=16176;
static constexpr int W_C2BW=16200, W_C2BB=16584, W_C211W=16616, W_C211B=18152;
static constexpr int W_KW=18184, W_KB=128776, W_ATTG=131848, W_GA1=131880;
static constexpr int W_TEMP=131976, W_QKVW=131984, W_QKVDW=138896, W_MPROJ=140192;
static constexpr int W_CA1W=142496, W_CA1B=144800, W_CA2W=144848, W_CA2B=147152;

__device__ __forceinline__ float b2f(ushortT u) {
    union { uint32_t i; float f; } v; v.i = ((uint32_t)u) << 16; return v.f;
}
__device__ __forceinline__ ushortT f2b(float f) {
    union { float f; uint32_t i; } v; v.f = f;
    uint32_t i = v.i;
    uint32_t lsb = (i >> 16) & 1u;
    i += 0x7fffu + lsb;
    return (ushortT)(i >> 16);
}
__device__ __forceinline__ int dtype_bf16(const uint32_t* n1w_raw) {
    return n1w_raw[0] == 0x3F803F80u;
}
__device__ __forceinline__ ushortT raw_bf(const void* p, int idx, int fl) {
    return fl ? ((const ushortT*)p)[idx] : f2b(((const float*)p)[idx]);
}
__device__ __forceinline__ float raw_f(const void* p, int idx, int fl) {
    return fl ? b2f(((const ushortT*)p)[idx]) : ((const float*)p)[idx];
}

// ---------------- prep: convert + all bf16 weight matrices + gap + LN ----------------
struct ConvPack {
    const void* src[27];
    int dstoff[27];
    int n[27];
};
struct RawW {
    const void* kdw1; const void* kc1a; const void* c211w; const void* qkvw;
    const void* kproj; const void* mproj; const void* kw; const void* kb;
    const void* n1w; const void* n1b; const void* n2w; const void* n2b;
};

__global__ void __launch_bounds__(256) k_prep(ConvPack p, RawW rw, float* __restrict__ dst,
                       ushortT* __restrict__ Wt, ushortT* __restrict__ Wpw,
                       ushortT* __restrict__ Wqk, ushortT* __restrict__ Wkp,
                       ushortT* __restrict__ Wmp,
                       const void* __restrict__ x, float* __restrict__ gap,
                       float* __restrict__ xn, ushortT* __restrict__ xnb,
                       ushortT* __restrict__ xmb,
                       const uint32_t* __restrict__ n1w_raw) {
    int fl = dtype_bf16(n1w_raw);
    int y = blockIdx.y;
    if (y < 27) {
        int n = p.n[y];
        for (int i = blockIdx.x * 256 + threadIdx.x; i < n; i += 64 * 256) {
            dst[p.dstoff[y] + i] = raw_f(p.src[y], i, fl);
        }
    } else if (y == 27) {
        for (int u = blockIdx.x * 256 + threadIdx.x; u < 24 * 160 * 32; u += 64 * 256) {
            int n = u & 31;
            int rest = u >> 5;
            int r = rest % 160;
            int gr = rest / 160;
            ushortT out;
            if (r < 144) {
                int j = r >> 2, i = r & 3;
                out = raw_bf(rw.kw, n * 3456 + gr * 144 + i * 36 + j, fl);
            } else if (r < 148) {
                out = raw_bf(rw.kb, n * HID + gr * 4 + (r - 144), fl);
            } else out = 0;
            Wt[u] = out;
        }
    } else if (y == 28) {
        for (int u = blockIdx.x * 256 + threadIdx.x; u < 224 * 64; u += 64 * 256) {
            int co = u >> 6, c = u & 63;
            ushortT v = 0;
            if (c < 48) {
                if (co < 96)       v = raw_bf(rw.kdw1,  co * 48 + c, fl);
                else if (co < 192) v = raw_bf(rw.kc1a,  (co - 96) * 48 + c, fl);
                else               v = raw_bf(rw.c211w, (co - 192) * 48 + c, fl);
            }
            Wpw[u] = v;
        }
    } else if (y == 29) {
        for (int u = blockIdx.x * 256 + threadIdx.x; u < 144 * 64; u += 64 * 256) {
            int co = u >> 6, c = u & 63;
            Wqk[u] = (c < 48) ? raw_bf(rw.qkvw, co * 48 + c, fl) : (ushortT)0;
        }
    } else if (y == 30) {
        for (int u = blockIdx.x * 256 + threadIdx.x; u < 48 * 96; u += 64 * 256) {
            int co = u / 96, c = u % 96;
            Wkp[u] = raw_bf(rw.kproj, co * 96 + c, fl);
        }
    } else if (y == 31) {
        for (int u = blockIdx.x * 256 + threadIdx.x; u < 48 * 64; u += 64 * 256) {
            int co = u >> 6, c = u & 63;
            Wmp[u] = (c < 48) ? raw_bf(rw.mproj, co * 48 + c, fl) : (ushortT)0;
        }
    } else if (y == 32) {
        __shared__ float red[4];
        for (int bc = blockIdx.x; bc < Bn * Cc; bc += 64) {
            float s = 0.f;
            if (fl) {
                const ushortT* xb = (const ushortT*)x + bc * HW;
                for (int i = threadIdx.x; i < HW; i += 256) s += b2f(xb[i]);
            } else {
                const float* xb = (const float*)x + bc * HW;
                for (int i = threadIdx.x; i < HW; i += 256) s += xb[i];
            }
            #pragma unroll
            for (int o = 32; o > 0; o >>= 1) s += __shfl_down(s, o);
            int lane = threadIdx.x & 63, wv = threadIdx.x >> 6;
            if (lane == 0) red[wv] = s;
            __syncthreads();
            if (threadIdx.x == 0)
                gap[bc] = (red[0] + red[1] + red[2] + red[3]) * (1.f / HW);
            __syncthreads();
        }
    } else {
        // LN1 + LN2, streaming (spill-free): pass 1 stats, pass 2 re-read (L1-hot) + emit
        int pp = blockIdx.x * 256 + threadIdx.x;
        int b = pp >> 12, hw = pp & 4095;
        const ushortT* xbh = (const ushortT*)x + b * Cc * HW + hw;
        const float*  xbf = (const float*)x + b * Cc * HW + hw;
        float s = 0.f, ss = 0.f;
        for (int c = 0; c < Cc; c++) {
            float v = fl ? b2f(xbh[c * HW]) : xbf[c * HW];
            s += v; ss += v * v;
        }
        float mu = s * (1.f / Cc);
        float var = ss * (1.f / Cc) - mu * mu;
        float r = rsqrtf(var + 1e-6f);
        uint4* dn = (uint4*)(xnb + (size_t)pp * 64);
        uint4* dm = (uint4*)(xmb + (size_t)pp * 64);
        for (int qd = 0; qd < 6; qd++) {
            uint32_t vn[4], vm[4];
            #pragma unroll
            for (int j = 0; j < 4; j++) {
                int c0 = qd * 8 + j * 2;
                float v0 = fl ? b2f(xbh[c0 * HW]) : xbf[c0 * HW];
                float v1 = fl ? b2f(xbh[(c0 + 1) * HW]) : xbf[(c0 + 1) * HW];
                float y0 = (v0 - mu) * r, y1 = (v1 - mu) * r;
                float n0 = raw_f(rw.n1w, c0, fl) * y0 + raw_f(rw.n1b, c0, fl);
                float n1 = raw_f(rw.n1w, c0 + 1, fl) * y1 + raw_f(rw.n1b, c0 + 1, fl);
                float m0 = raw_f(rw.n2w, c0, fl) * y0 + raw_f(rw.n2b, c0, fl);
                float m1 = raw_f(rw.n2w, c0 + 1, fl) * y1 + raw_f(rw.n2b, c0 + 1, fl);
                xn[(b * Cc + c0) * HW + hw] = n0;
                xn[(b * Cc + c0 + 1) * HW + hw] = n1;
                vn[j] = (uint32_t)f2b(n0) | ((uint32_t)f2b(n1) << 16);
                vm[j] = (uint32_t)f2b(m0) | ((uint32_t)f2b(m1) << 16);
            }
            uint4 un; un.x = vn[0]; un.y = vn[1]; un.z = vn[2]; un.w = vn[3];
            uint4 um; um.x = vm[0]; um.y = vm[1]; um.z = vm[2]; um.w = vm[3];
            dn[qd] = un;
            dm[qd] = um;
        }
        uint4 zz; zz.x = 0; zz.y = 0; zz.z = 0; zz.w = 0;
        dn[6] = zz; dn[7] = zz;
        dm[6] = zz; dm[7] = zz;
    }
}

// ---------------- pw1m: y=0 [224x48]@xnb -> t1,t2,attn_t ; y=1 [144x48]@xmb -> qkvr. grid (256,2) x 256 ----------------
__global__ void __launch_bounds__(256) k_pw1m(const ushortT* __restrict__ xnb, const ushortT* __restrict__ xmb,
                       const ushortT* __restrict__ Wpw, const ushortT* __restrict__ Wqk,
                       const float* __restrict__ wts, float* __restrict__ t1,
                       float* __restrict__ t2, float* __restrict__ attn_t,
                       float* __restrict__ qkvr) {
    int wave = threadIdx.x >> 6, lane = threadIdx.x & 63;
    int m = lane & 15, q = lane >> 4;
    int p = blockIdx.x * 64 + wave * 16 + m;
    int b = p >> 12, hw = p & 4095;
    if (blockIdx.y == 0) {
        short8 B0 = *(const short8*)(xnb + (size_t)p * 64 + q * 8);
        short8 B1 = *(const short8*)(xnb + (size_t)p * 64 + 32 + q * 8);
        #pragma unroll
        for (int t = 0; t < 14; t++) {
            short8 A0 = *(const short8*)(Wpw + (16 * t + m) * 64 + q * 8);
            short8 A1 = *(const short8*)(Wpw + (16 * t + m) * 64 + 32 + q * 8);
            f32x4 z = {0.f, 0.f, 0.f, 0.f};
            f32x4 D = __builtin_amdgcn_mfma_f32_16x16x32_bf16(A0, B0, z, 0, 0, 0);
            D = __builtin_amdgcn_mfma_f32_16x16x32_bf16(A1, B1, D, 0, 0, 0);
            #pragma unroll
            for (int g = 0; g < 4; g++) {
                int co = 16 * t + 4 * q + g;
                if (t < 6) t1[(b * HID + co) * HW + hw] = D[g];
                else if (t < 12) t2[(b * HID + (co - 96)) * HW + hw] = D[g];
                else {
                    int n = co - 192;
                    attn_t[(size_t)p * 32 + n] = D[g] + wts[W_C211B + n];
                }
            }
        }
    } else {
        short8 C0 = *(const short8*)(xmb + (size_t)p * 64 + q * 8);
        short8 C1 = *(const short8*)(xmb + (size_t)p * 64 + 32 + q * 8);
        #pragma unroll
        for (int t = 0; t < 9; t++) {
            short8 A0 = *(const short8*)(Wqk + (16 * t + m) * 64 + q * 8);
            short8 A1 = *(const short8*)(Wqk + (16 * t + m) * 64 + 32 + q * 8);
            f32x4 z = {0.f, 0.f, 0.f, 0.f};
            f32x4 D = __builtin_amdgcn_mfma_f32_16x16x32_bf16(A0, C0, z, 0, 0, 0);
            D = __builtin_amdgcn_mfma_f32_16x16x32_bf16(A1, C1, D, 0, 0, 0);
            #pragma unroll
            for (int g = 0; g < 4; g++) {
                int co = 16 * t + 4 * q + g;
                qkvr[(b * 144 + co) * HW + hw] = D[g];
            }
        }
    }
}

// ---------------- dw: y<96 kdw2->gelu->x1g ; y<192 kc1b->uf ; y<216 c2a->araw ; y<360 qkvdw->qkv. grid (16, 360) ----------------
__global__ void __launch_bounds__(256) k_dw(const float* __restrict__ t1, const float* __restrict__ t2,
                     const float* __restrict__ xn, const float* __restrict__ qkvr,
                     const float* __restrict__ wts,
                     float* __restrict__ x1g, float* __restrict__ uf,
                     float* __restrict__ araw, float* __restrict__ qkv) {
    int y = blockIdx.y;
    int pbase = blockIdx.x * 1024 + threadIdx.x * 4;
    int b = pbase >> 12, hw = pbase & 4095, h = hw >> 6, w0 = hw & 63;

    if (y < 192) {
        int c = (y < 96) ? y : y - 96;
        const float* base = (y < 96) ? t1 : t2;
        const float* wk = wts + ((y < 96) ? W_KDW2 : W_KC1B) + c * 9;
        const float* plane = base + (b * HID + c) * HW;

        float a0 = 0.f, a1 = 0.f, a2 = 0.f, a3 = 0.f;
        #pragma unroll
        for (int ki = 0; ki < 3; ki++) {
            int hh = h + ki - 1;
            if ((unsigned)hh < 64u) {
                const float* row = plane + hh * 64 + w0;
                float4 mm = *(const float4*)row;
                float lf = (w0 > 0) ? row[-1] : 0.f;
                float rt = (w0 < 60) ? row[4] : 0.f;
                float k0 = wk[ki * 3], k1 = wk[ki * 3 + 1], k2 = wk[ki * 3 + 2];
                a0 += k0 * lf   + k1 * mm.x + k2 * mm.y;
                a1 += k0 * mm.x + k1 * mm.y + k2 * mm.z;
                a2 += k0 * mm.y + k1 * mm.z + k2 * mm.w;
                a3 += k0 * mm.z + k1 * mm.w + k2 * rt;
            }
        }
        int idx = (b * HID + c) * HW + hw;
        if (y < 96) {
            float4 g;
            g.x = 0.5f * a0 * (1.f + erff(a0 * 0.70710678118654752f));
            g.y = 0.5f * a1 * (1.f + erff(a1 * 0.70710678118654752f));
            g.z = 0.5f * a2 * (1.f + erff(a2 * 0.70710678118654752f));
            g.w = 0.5f * a3 * (1.f + erff(a3 * 0.70710678118654752f));
            *(float4*)(x1g + idx) = g;
        } else {
            float4 o; o.x = a0; o.y = a1; o.z = a2; o.w = a3;
            *(float4*)(uf + idx) = o;
        }
    } else if (y < 216) {
        int o = y - 192;
        float bias = wts[W_C2AB + o];
        float a0 = bias, a1 = bias, a2 = bias, a3 = bias;
        #pragma unroll
        for (int ic = 0; ic < 2; ic++) {
            const float* plane = xn + (b * Cc + 2 * o + ic) * HW;
            const float* wk = wts + W_C2AW + (o * 2 + ic) * 9;
            #pragma unroll
            for (int ki = 0; ki < 3; ki++) {
                int hh = h + ki - 1;
                if ((unsigned)hh < 64u) {
                    const float* row = plane + hh * 64 + w0;
                    float4 mm = *(const float4*)row;
                    float lf = (w0 > 0) ? row[-1] : 0.f;
                    float rt = (w0 < 60) ? row[4] : 0.f;
                    float k0 = wk[ki * 3], k1 = wk[ki * 3 + 1], k2 = wk[ki * 3 + 2];
                    a0 += k0 * lf   + k1 * mm.x + k2 * mm.y;
                    a1 += k0 * mm.x + k1 * mm.y + k2 * mm.z;
                    a2 += k0 * mm.y + k1 * mm.z + k2 * mm.w;
                    a3 += k0 * mm.z + k1 * mm.w + k2 * rt;
                }
            }
        }
        float4 out; out.x = a0; out.y = a1; out.z = a2; out.w = a3;
        *(float4*)(araw + (b * INTERC + o) * HW + hw) = out;
    } else {
        int ch = y - 216;   // 0..143
        const float* wk = wts + W_QKVDW + ch * 9;
        const float* plane = qkvr + (b * 144 + ch) * HW;

        float a0 = 0.f, a1 = 0.f, a2 = 0.f, a3 = 0.f;
        #pragma unroll
        for (int ki = 0; ki < 3; ki++) {
            int hh = h + ki - 1;
            if ((unsigned)hh < 64u) {
                const float* row = plane + hh * 64 + w0;
                float4 mm = *(const float4*)row;
                float lf = (w0 > 0) ? row[-1] : 0.f;
                float rt = (w0 < 60) ? row[4] : 0.f;
                float k0 = wk[ki * 3], k1 = wk[ki * 3 + 1], k2 = wk[ki * 3 + 2];
                a0 += k0 * lf   + k1 * mm.x + k2 * mm.y;
                a1 += k0 * mm.x + k1 * mm.y + k2 * mm.z;
                a2 += k0 * mm.y + k1 * mm.z + k2 * mm.w;
                a3 += k0 * mm.z + k1 * mm.w + k2 * rt;
            }
        }
        float4 o; o.x = a0; o.y = a1; o.z = a2; o.w = a3;
        *(float4*)(qkv + (b * 144 + ch) * HW + hw) = o;
    }
}

// ---------------- attsm: x<64 att(SimpleGate+c2b)->att_bf ; x>=64 smat partials. grid (192) x 256 ----------------
__global__ void __launch_bounds__(256) k_attsm(const float* __restrict__ araw, const float* __restrict__ attn_t,
                       const float* __restrict__ qkv, const float* __restrict__ wts,
                       ushortT* __restrict__ att_bf, float* __restrict__ Sp) {
    if (blockIdx.x < 64) {
        int p = blockIdx.x * 256 + threadIdx.x;
        int b = p >> 12, hw = p & 4095;
        const float* ab = araw + b * INTERC * HW + hw;
        float sg[12];
        #pragma unroll
        for (int i = 0; i < 12; i++) sg[i] = ab[i * HW] * ab[(12 + i) * HW];
        const float* ct = attn_t + (size_t)p * 32;
        uint32_t packed[16];
        #pragma unroll
        for (int nq = 0; nq < 16; nq++) {
            float v2[2];
            #pragma unroll
            for (int u = 0; u < 2; u++) {
                int n = nq * 2 + u;
                float a = wts[W_C2BB + n];
                #pragma unroll
                for (int c = 0; c < 12; c++) a += wts[W_C2BW + n * 12 + c] * sg[c];
                v2[u] = wts[W_ATTG + n] * a + ct[n];
            }
            packed[nq] = (uint32_t)f2b(v2[0]) | ((uint32_t)f2b(v2[1]) << 16);
        }
        uint4* dst = (uint4*)(att_bf + (size_t)p * 32);
        #pragma unroll
        for (int qd = 0; qd < 4; qd++) {
            uint4 v; v.x = packed[qd*4]; v.y = packed[qd*4+1]; v.z = packed[qd*4+2]; v.w = packed[qd*4+3];
            dst[qd] = v;
        }
    } else {
        int sub = blockIdx.x - 64;          // 0..127
        int bh = sub & 31, chunk = sub >> 5;
        int b = bh / HEADS, hd = bh % HEADS;
        const float* qb = qkv + (b * 144 + hd * CPH) * HW;
        const float* kb = qkv + (b * 144 + 48 + hd * CPH) * HW;
        float acc[48];
        #pragma unroll
        for (int t = 0; t < 48; t++) acc[t] = 0.f;
        #pragma unroll
        for (int i = 0; i < 4; i++) {
            int px = chunk * 1024 + i * 256 + threadIdx.x;
            float qv[CPH], kv[CPH];
            #pragma unroll
            for (int c = 0; c < CPH; c++) { qv[c] = qb[c * HW + px]; kv[c] = kb[c * HW + px]; }
            #pragma unroll
            for (int c = 0; c < CPH; c++) {
                #pragma unroll
                for (int d = 0; d < CPH; d++) acc[c * CPH + d] += qv[c] * kv[d];
                acc[36 + c] += qv[c] * qv[c];
                acc[42 + c] += kv[c] * kv[c];
            }
        }
        __shared__ float red[48 * 4];
        int lane = threadIdx.x & 63, wv = threadIdx.x >> 6;
        #pragma unroll
        for (int t = 0; t < 48; t++) {
            float v = acc[t];
            #pragma unroll
            for (int o = 32; o > 0; o >>= 1) v += __shfl_down(v, o);
            if (lane == 0) red[t * 4 + wv] = v;
        }
        __syncthreads();
        if (threadIdx.x < 48)
            Sp[(bh * 4 + chunk) * 48 + threadIdx.x] =
                red[threadIdx.x * 4] + red[threadIdx.x * 4 + 1] +
                red[threadIdx.x * 4 + 2] + red[threadIdx.x * 4 + 3];
    }
}

// ---------------- KBA core via MFMA -> h_bf [p][96] bf16. grid (64,24) x 256 ----------------
__global__ void __launch_bounds__(256) k_kba(const ushortT* __restrict__ att_bf, const float* __restrict__ uf,
                     const float* __restrict__ x1g, const ushortT* __restrict__ Wt,
                     const float* __restrict__ wts, ushortT* __restrict__ h_bf) {
    int wave = threadIdx.x >> 6, lane = threadIdx.x & 63;
    int m = lane & 15, q = lane >> 4;
    int gr = blockIdx.y;

    short8 A[10];
    const ushortT* wtg = Wt + gr * 160 * 32;
    #pragma unroll
    for (int t = 0; t < 10; t++)
        A[t] = *(const short8*)(wtg + (16 * t + m) * 32 + q * 8);

    for (int tile = 0; tile < 4; tile++) {
        int p = blockIdx.x * 256 + wave * 64 + tile * 16 + m;
        int b = p >> 12, hw = p & 4095, h = hw >> 6, w = hw & 63;

        short8 Bf = *(const short8*)(att_bf + (size_t)p * 32 + q * 8);

        f32x4 D[10];
        #pragma unroll
        for (int t = 0; t < 10; t++) {
            f32x4 z = {0.f, 0.f, 0.f, 0.f};
            D[t] = __builtin_amdgcn_mfma_f32_16x16x32_bf16(A[t], Bf, z, 0, 0, 0);
        }

        float s0 = 0.f, s1 = 0.f, s2 = 0.f, s3 = 0.f;
        #pragma unroll
        for (int t = 0; t < 9; t++) {
            int j = 4 * t + q;
            int ci = j / 9;
            int kk = j - 9 * ci;
            int ki = kk / 3, kj = kk - 3 * ki;
            int hh = h + ki - 1, ww = w + kj - 1;
            float tap = 0.f;
            if ((unsigned)hh < 64u && (unsigned)ww < 64u)
                tap = uf[(b * HID + gr * 4 + ci) * HW + hh * 64 + ww];
            s0 += D[t][0] * tap;
            s1 += D[t][1] * tap;
            s2 += D[t][2] * tap;
            s3 += D[t][3] * tap;
        }
        s0 += D[9][0]; s1 += D[9][1]; s2 += D[9][2]; s3 += D[9][3];

        s0 += __shfl_xor(s0, 16); s0 += __shfl_xor(s0, 32);
        s1 += __shfl_xor(s1, 16); s1 += __shfl_xor(s1, 32);
        s2 += __shfl_xor(s2, 16); s2 += __shfl_xor(s2, 32);
        s3 += __shfl_xor(s3, 16); s3 += __shfl_xor(s3, 32);

        float sel = (q == 0) ? s0 : ((q == 1) ? s1 : ((q == 2) ? s2 : s3));
        int ch = gr * 4 + q;
        int idx = (b * HID + ch) * HW + hw;
        float x2 = sel * wts[W_GA1 + ch] + uf[idx];
        float hv = x1g[idx] * x2;
        h_bf[(size_t)p * 96 + ch] = f2b(hv);
    }
}

// ---------------- finalm: softmax(Sp)+ca in-block; kproj-MFMA + S@v + mproj-MFMA + residual. grid 256 x 256 ----------------
__global__ void __launch_bounds__(256) k_finalm(const void* __restrict__ x, const uint32_t* __restrict__ n1w_raw,
                        const ushortT* __restrict__ h_bf, const ushortT* __restrict__ Wkp,
                        const ushortT* __restrict__ Wmp, const float* __restrict__ qkv,
                        const float* __restrict__ Sp, const float* __restrict__ gap,
                        const float* __restrict__ wts, void* __restrict__ out) {
    int fl = dtype_bf16(n1w_raw);
    int wave = threadIdx.x >> 6, lane = threadIdx.x & 63;
    int m = lane & 15, q = lane >> 4;
    int p = blockIdx.x * 64 + wave * 16 + m;
    int hw = p & 4095;
    int bblk = (blockIdx.x * 64) >> 12;

    __shared__ float sm[384];
    __shared__ float S_l[288];
    __shared__ float caL[96];
    for (int i = threadIdx.x; i < 384; i += 256) {
        int hd = i / 48, k = i % 48;
        int bh = bblk * HEADS + hd;
        sm[i] = Sp[(bh * 4 + 0) * 48 + k] + Sp[(bh * 4 + 1) * 48 + k]
              + Sp[(bh * 4 + 2) * 48 + k] + Sp[(bh * 4 + 3) * 48 + k];
    }
    __syncthreads();
    if (threadIdx.x < 48) {
        int hd = threadIdx.x / 6, c = threadIdx.x % 6;
        const float* base = sm + hd * 48;
        float rqv = 1.f / fmaxf(sqrtf(base[36 + c]), 1e-12f);
        float tmp = wts[W_TEMP + hd];
        float row[CPH];
        #pragma unroll
        for (int d = 0; d < CPH; d++) {
            float rkv = 1.f / fmaxf(sqrtf(base[42 + d]), 1e-12f);
            row[d] = base[c * CPH + d] * rqv * rkv * tmp;
        }
        float mx = row[0];
        #pragma unroll
        for (int d = 1; d < CPH; d++) mx = fmaxf(mx, row[d]);
        float sum = 0.f;
        #pragma unroll
        for (int d = 0; d < CPH; d++) { row[d] = expf(row[d] - mx); sum += row[d]; }
        float inv = 1.f / sum;
        #pragma unroll
        for (int d = 0; d < CPH; d++) S_l[hd * 36 + c * CPH + d] = row[d] * inv;
    }
    if (threadIdx.x >= 64 && threadIdx.x < 160) {
        int i = threadIdx.x - 64;
        int which = i / 48, co = i % 48;
        const float* g = gap + bblk * Cc;
        float sacc = wts[(which ? W_CA2B : W_CA1B) + co];
        #pragma unroll
        for (int c = 0; c < Cc; c++)
            sacc += wts[(which ? W_CA2W : W_CA1W) + co * Cc + c] * g[c];
        caL[i] = sacc;
    }
    __syncthreads();

    // kproj: Dk = Wkp @ h_bf[p]
    short8 H0 = *(const short8*)(h_bf + (size_t)p * 96 + q * 8);
    short8 H1 = *(const short8*)(h_bf + (size_t)p * 96 + 32 + q * 8);
    short8 H2 = *(const short8*)(h_bf + (size_t)p * 96 + 64 + q * 8);
    f32x4 Dk[3];
    #pragma unroll
    for (int t = 0; t < 3; t++) {
        short8 A0 = *(const short8*)(Wkp + (16 * t + m) * 96 + q * 8);
        short8 A1 = *(const short8*)(Wkp + (16 * t + m) * 96 + 32 + q * 8);
        short8 A2 = *(const short8*)(Wkp + (16 * t + m) * 96 + 64 + q * 8);
        f32x4 z = {0.f, 0.f, 0.f, 0.f};
        f32x4 D = __builtin_amdgcn_mfma_f32_16x16x32_bf16(A0, H0, z, 0, 0, 0);
        D = __builtin_amdgcn_mfma_f32_16x16x32_bf16(A1, H1, D, 0, 0, 0);
        Dk[t] = __builtin_amdgcn_mfma_f32_16x16x32_bf16(A2, H2, D, 0, 0, 0);
    }

    // mdta B-fragments via S@v for this pixel
    const float* vbase = qkv + (bblk * 144 + 96) * HW + hw;
    short8 Bm0, Bm1;
    #pragma unroll
    for (int jj = 0; jj < 8; jj++) {
        int c0 = q * 8 + jj;
        int hd0 = c0 / 6, cc0 = c0 - 6 * hd0;
        float a = 0.f;
        #pragma unroll
        for (int d = 0; d < CPH; d++)
            a += S_l[hd0 * 36 + cc0 * 6 + d] * vbase[(hd0 * 6 + d) * HW];
        Bm0[jj] = (short)f2b(a);
        int c1 = 32 + q * 8 + jj;
        float bv = 0.f;
        if (c1 < 48) {
            int hd1 = c1 / 6, cc1 = c1 - 6 * hd1;
            #pragma unroll
            for (int d = 0; d < CPH; d++)
                bv += S_l[hd1 * 36 + cc1 * 6 + d] * vbase[(hd1 * 6 + d) * HW];
        }
        Bm1[jj] = (short)f2b(bv);
    }

    // mproj + epilogue
    #pragma unroll
    for (int t = 0; t < 3; t++) {
        short8 A0 = *(const short8*)(Wmp + (16 * t + m) * 64 + q * 8);
        short8 A1 = *(const short8*)(Wmp + (16 * t + m) * 64 + 32 + q * 8);
        f32x4 z = {0.f, 0.f, 0.f, 0.f};
        f32x4 D = __builtin_amdgcn_mfma_f32_16x16x32_bf16(A0, Bm0, z, 0, 0, 0);
        D = __builtin_amdgcn_mfma_f32_16x16x32_bf16(A1, Bm1, D, 0, 0, 0);
        #pragma unroll
        for (int g = 0; g < 4; g++) {
            int co = 16 * t + 4 * q + g;
            int idx = (bblk * Cc + co) * HW + hw;
            float xv = fl ? b2f(((const ushortT*)x)[idx]) : ((const float*)x)[idx];
            float res = xv + Dk[t][g] * caL[co] + D[g] * caL[48 + co];
            if (fl) ((ushortT*)out)[idx] = f2b(res);
            else    ((float*)out)[idx] = res;
        }
    }
}

// ---------------- host launch ----------------
extern "C" void kernel_launch(void* const* d_in, const int* in_sizes, int n_in,
                              void* d_out, int out_size, void* d_ws, size_t ws_size,
                              hipStream_t stream) {
    float* ws_f = (float*)d_ws;

    float* xn    = ws_f + FXN;
    float* bufA  = ws_f + FA;     // t1
    float* bufB  = ws_f + FB;     // t2
    float* x1g   = ws_f + FC;
    float* uf    = ws_f + FD;
    float* araw  = ws_f + FARAW;
    float* attn_t= ws_f + FATT;
    float* gap   = ws_f + FGAP;
    float* Sp    = ws_f + FSP;
    float* wts   = ws_f + FW;
    ushortT* att_bf  = (ushortT*)(ws_f + FATTB);
    ushortT* Wt      = (ushortT*)(ws_f + FWT);
    ushortT* xnb     = (ushortT*)(ws_f + FXNB);
    ushortT* xmb     = (ushortT*)(ws_f + FXMB);
    ushortT* h_bf    = (ushortT*)(ws_f + FHBF);
    ushortT* Wpw     = (ushortT*)(ws_f + FWPW);
    ushortT* Wqk     = (ushortT*)(ws_f + FWQK);
    ushortT* Wkp     = (ushortT*)(ws_f + FWKP);
    ushortT* Wmp     = (ushortT*)(ws_f + FWMP);
    float* qkvr      = ws_f + FQKVR;
    float* qkv       = ws_f + FQKV;   // dedicated - no aliasing with x1g/uf

    const uint32_t* n1w_raw = (const uint32_t*)d_in[1];

    static const int wsizes[27] = {48,48,48,48,4608,864,4608,864,4608,432,24,384,32,
                                   1536,32,110592,3072,32,96,8,6912,1296,2304,2304,48,2304,48};
    static const int woffs[27] = {W_N1W,W_N1B,W_N2W,W_N2B,W_KDW1,W_KDW2,W_KC1A,W_KC1B,
                                  W_KPROJ,W_C2AW,W_C2AB,W_C2BW,W_C2BB,W_C211W,W_C211B,
                                  W_KW,W_KB,W_ATTG,W_GA1,W_TEMP,W_QKVW,W_QKVDW,W_MPROJ,
                                  W_CA1W,W_CA1B,W_CA2W,W_CA2B};
    ConvPack cp;
    for (int i = 0; i < 27; i++) {
        cp.src[i] = d_in[i + 1];
        cp.dstoff[i] = woffs[i];
        cp.n[i] = wsizes[i];
    }
    RawW rw;
    rw.kdw1 = d_in[5]; rw.kc1a = d_in[7]; rw.c211w = d_in[14]; rw.qkvw = d_in[21];
    rw.kproj = d_in[9]; rw.mproj = d_in[23]; rw.kw = d_in[16]; rw.kb = d_in[17];
    rw.n1w = d_in[1]; rw.n1b = d_in[2]; rw.n2w = d_in[3]; rw.n2b = d_in[4];

    k_prep<<<dim3(64, 34), 256, 0, stream>>>(cp, rw, wts, Wt, Wpw, Wqk, Wkp, Wmp,
                                             d_in[0], gap, xn, xnb, xmb, n1w_raw);
    k_pw1m<<<dim3(256, 2), 256, 0, stream>>>(xnb, xmb, Wpw, Wqk, wts, bufA, bufB, attn_t, qkvr);
    k_dw<<<dim3(16, 360), 256, 0, stream>>>(bufA, bufB, xn, qkvr, wts, x1g, uf, araw, qkv);
    k_attsm<<<dim3(192), 256, 0, stream>>>(araw, attn_t, qkv, wts, att_bf, Sp);
    k_kba<<<dim3(64, 24), 256, 0, stream>>>(att_bf, uf, x1g, Wt, wts, h_bf);
    k_finalm<<<dim3(256), 256, 0, stream>>>(d_in[0], n1w_raw, h_bf, Wkp, Wmp,
                                            qkv, Sp, gap, wts, d_out);
}